// Round 5
// baseline (2388.541 us; speedup 1.0000x reference)
//
#include <hip/hip_runtime.h>

// ---------------------------------------------------------------------------
// Transducer forward (RNN-T). R4: sentinel-synced persistent LSTMs with
// BATCHED optimistic polling (all words in flight per iteration, not a
// serialized per-word spin).
//   WGs  0-15 : encoder L0 (256 steps), 32 units/WG, Whh0 in LDS
//   WGs 16-47 : encoder L1 (256 steps), 16 units/WG, [Whh1|Wih1] K=1024 in LDS
//   WGs 48-63 : decoder   (65 steps),  32 units/WG, dWhh in LDS
// h exchange: per-step write-once buffers hseq[t+1], pre-filled with sentinel
// 0xFFFFFFFF (f16 NaN pair; h in (-1,1) can never produce it). Consumers poll
// the data words directly. RELAXED agent-scope atomics throughout.
// ---------------------------------------------------------------------------

typedef _Float16 f16;
typedef _Float16 f16x8 __attribute__((ext_vector_type(8)));
typedef float f32x4 __attribute__((ext_vector_type(4)));
using u32 = unsigned int;

#define BB   8
#define TT   256
#define UU1  65      // U+1
#define HH   512
#define G4   2048    // 4*H
#define PP   512
#define JJ   512
#define VV   1024
#define SENT 0xFFFFFFFFu

#define LOADX(p)     __hip_atomic_load((p), __ATOMIC_RELAXED, __HIP_MEMORY_SCOPE_AGENT)
#define STOREX(p, v) __hip_atomic_store((p), (v), __ATOMIC_RELAXED, __HIP_MEMORY_SCOPE_AGENT)

static __device__ __forceinline__ u32 packf16(float a, float b) {
  f16 ha = (f16)a, hb = (f16)b;
  unsigned short ua = __builtin_bit_cast(unsigned short, ha);
  unsigned short ub = __builtin_bit_cast(unsigned short, hb);
  return (u32)ua | ((u32)ub << 16);
}
static __device__ __forceinline__ float sigm(float x) {
  x = fminf(30.f, fmaxf(-30.f, x));
  return __builtin_amdgcn_rcpf(1.f + __expf(-x));
}
static __device__ __forceinline__ float ftanh(float x) {
  x = fminf(15.f, fmaxf(-15.f, x));
  float t = __expf(2.f * x);
  return (t - 1.f) * __builtin_amdgcn_rcpf(t + 1.f);
}

// ---------------------------- utility kernels ------------------------------
__global__ void k_zero(u32* __restrict__ p, int n) {
  int i = blockIdx.x * 256 + threadIdx.x;
  if (i < n) p[i] = 0u;
}
__global__ void k_fill(u32* __restrict__ p, int n, u32 v) {
  int i = blockIdx.x * 256 + threadIdx.x;
  if (i < n) p[i] = v;
}

__global__ void k_cast(const float* __restrict__ s, f16* __restrict__ d, int n4) {
  int i = blockIdx.x * 256 + threadIdx.x;
  if (i < n4) {
    const float4 v = *(const float4*)(s + (size_t)i * 4);
    uint2 p; p.x = packf16(v.x, v.y); p.y = packf16(v.z, v.w);
    *(uint2*)(d + (size_t)i * 4) = p;
  }
}

// e[row][0:512] = embed[ys_p[row]] ; row = b*65+u ; ys_p[b][0]=BOS=0
__global__ void k_embed(const int* __restrict__ ys, const float* __restrict__ emb,
                        float* __restrict__ e) {
  int row = blockIdx.x;                 // 0..519
  int b = row / UU1, u = row % UU1;
  int idx = (u == 0) ? 0 : ys[b * (UU1 - 1) + (u - 1)];
  const float4* s = (const float4*)(emb + (size_t)idx * HH);
  float4* d = (float4*)(e + (size_t)row * HH);
  d[threadIdx.x] = s[threadIdx.x];      // 128 threads x 16B = 2KB
}

// ------------------------------ generic GEMM -------------------------------
// C[M,N] = A[M,lda](f32) * B[N,ldb](f16)^T (+ bias[n]); MFMA f16 16x16x32.
__global__ __launch_bounds__(256) void k_gemm(
    const float* __restrict__ A, const f16* __restrict__ B,
    const float* __restrict__ bias, float* __restrict__ C,
    int M, int N, int K, int lda, int ldb) {
  __shared__ f16 As[128][72];
  __shared__ f16 Bs[128][72];
  int tid = threadIdx.x;
  int mb = blockIdx.y * 128, nb = blockIdx.x * 128;
  int wave = tid >> 6, lane = tid & 63;
  int wm = wave >> 1, wn = wave & 1;
  int rowa = lane & 15, kg = lane >> 4;
  f32x4 acc[4][4] = {};
  for (int k0 = 0; k0 < K; k0 += 64) {
    for (int idx = tid; idx < 2048; idx += 256) {
      int r = idx >> 4, cq = idx & 15;
      int gm = mb + r, gk = k0 + cq * 4;
      float4 v = make_float4(0.f, 0.f, 0.f, 0.f);
      if (gm < M && gk + 3 < K) v = *(const float4*)(A + (size_t)gm * lda + gk);
      uint2 p; p.x = packf16(v.x, v.y); p.y = packf16(v.z, v.w);
      *(uint2*)&As[r][cq * 4] = p;
    }
    for (int idx = tid; idx < 1024; idx += 256) {
      int r = idx >> 3, c8 = idx & 7;
      int gn = nb + r, gk = k0 + c8 * 8;
      uint4 v = make_uint4(0u, 0u, 0u, 0u);
      if (gn < N && gk + 7 < K) v = *(const uint4*)(B + (size_t)gn * ldb + gk);
      *(uint4*)&Bs[r][c8 * 8] = v;
    }
    __syncthreads();
#pragma unroll
    for (int kf = 0; kf < 2; ++kf) {
      f16x8 af[4], bf[4];
#pragma unroll
      for (int mt = 0; mt < 4; ++mt)
        af[mt] = *(const f16x8*)&As[wm * 64 + mt * 16 + rowa][kf * 32 + kg * 8];
#pragma unroll
      for (int nt = 0; nt < 4; ++nt)
        bf[nt] = *(const f16x8*)&Bs[wn * 64 + nt * 16 + rowa][kf * 32 + kg * 8];
#pragma unroll
      for (int mt = 0; mt < 4; ++mt)
#pragma unroll
        for (int nt = 0; nt < 4; ++nt)
          acc[mt][nt] = __builtin_amdgcn_mfma_f32_16x16x32_f16(af[mt], bf[nt], acc[mt][nt], 0, 0, 0);
    }
    __syncthreads();
  }
#pragma unroll
  for (int nt = 0; nt < 4; ++nt) {
    int gn = nb + wn * 64 + nt * 16 + rowa;
    float bv = bias ? bias[gn] : 0.f;
#pragma unroll
    for (int mt = 0; mt < 4; ++mt)
#pragma unroll
      for (int r = 0; r < 4; ++r) {
        int gm = mb + wm * 64 + mt * 16 + kg * 4 + r;
        if (gm < M) C[(size_t)gm * N + gn] = acc[mt][nt][r] + bv;
      }
  }
}

// --------------------- persistent LSTM, sentinel-synced --------------------
// Batched optimistic poll of NW words (NW independent loads in flight/iter).
template <int NW>
static __device__ __forceinline__ void poll_batch(const u32* const* p, u32* vv) {
#pragma unroll
  for (int k = 0; k < NW; ++k) vv[k] = SENT;
  int gd = 0;
  bool any = true;
  while (any && ++gd < (1 << 20)) {
    any = false;
#pragma unroll
    for (int k = 0; k < NW; ++k)
      if (vv[k] == SENT) {
        vv[k] = LOADX(p[k]);
        any = any | (vv[k] == SENT);
      }
  }
}

// 32-unit WG (L0 / decoder): LDS W[128][520], H[8][520], gat[8][132].
static __device__ __forceinline__ void lstm_16(
    int wg, const float* __restrict__ xp, const f16* __restrict__ Whh,
    u32* __restrict__ hseq,   // [S+1][2048]; slot 0 zeroed, rest sentinel
    float* __restrict__ hs, int S) {
  extern __shared__ char smem[];
  f16 (*W)[520] = (f16(*)[520])smem;                       // 133,120 B
  f16 (*H)[520] = (f16(*)[520])(smem + 133120);            //   8,320 B
  float (*gat)[132] = (float(*)[132])(smem + 133120 + 8320);
  const int tid = threadIdx.x;
  const int u0 = wg * 32;
  const int wave = tid >> 6, lane = tid & 63;
  const int rowa = lane & 15, kg = lane >> 4;
  const int b = tid >> 5, j = tid & 31;

  // stage Whh slice: LDS row r = g*32+i <-> global row g*512 + u0 + i
  for (int idx = tid; idx < 128 * 64; idx += 256) {
    int r = idx >> 6, ck = idx & 63;
    int g = r >> 5, i = r & 31;
    uint4 v = *(const uint4*)(Whh + ((size_t)(g * 512 + u0 + i)) * 512 + ck * 8);
    *(uint4*)&W[r][ck * 8] = v;
  }
  __syncthreads();

  float c = 0.f;
  for (int t = 0; t < S; ++t) {
    // xp loads issued FIRST -> in flight during the poll
    size_t xpo = ((size_t)b * S + t) * (size_t)G4 + u0 + j;
    float xi = xp[xpo], xf = xp[xpo + 512], xg = xp[xpo + 1024], xo = xp[xpo + 1536];

    // batched poll+stage h(t-1) = hseq[t] (8 words/thread, all in flight)
    const u32* hb = hseq + (size_t)t * 2048;
    const u32* ptr[8];
    u32 vv[8];
#pragma unroll
    for (int k = 0; k < 8; ++k) ptr[k] = hb + ((tid + k * 256) >> 8) * 256 + ((tid + k * 256) & 255);
    poll_batch<8>(ptr, vv);
#pragma unroll
    for (int k = 0; k < 8; ++k) {
      int idx = tid + k * 256;
      ((u32*)H)[(idx >> 8) * 260 + (idx & 255)] = vv[k];
    }
    __syncthreads();  // B2: H ready

    f32x4 acc0 = {0.f, 0.f, 0.f, 0.f}, acc1 = {0.f, 0.f, 0.f, 0.f};
#pragma unroll
    for (int kf = 0; kf < 16; ++kf) {
      f16x8 af = {};
      if (rowa < 8) af = *(const f16x8*)&H[rowa][kf * 32 + kg * 8];
      f16x8 b0 = *(const f16x8*)&W[wave * 32 + rowa][kf * 32 + kg * 8];
      f16x8 b1 = *(const f16x8*)&W[wave * 32 + 16 + rowa][kf * 32 + kg * 8];
      acc0 = __builtin_amdgcn_mfma_f32_16x16x32_f16(af, b0, acc0, 0, 0, 0);
      acc1 = __builtin_amdgcn_mfma_f32_16x16x32_f16(af, b1, acc1, 0, 0, 0);
    }
    if (kg < 2) {   // C rows 0..7 valid (batch)
#pragma unroll
      for (int r = 0; r < 4; ++r) {
        gat[kg * 4 + r][wave * 32 + rowa] = acc0[r];
        gat[kg * 4 + r][wave * 32 + 16 + rowa] = acc1[r];
      }
    }
    __syncthreads();  // B3: gat ready

    float gi = gat[b][j] + xi;
    float gf = gat[b][32 + j] + xf;
    float gg = gat[b][64 + j] + xg;
    float go = gat[b][96 + j] + xo;
    c = sigm(gf) * c + sigm(gi) * ftanh(gg);
    float h = sigm(go) * ftanh(c);

    float hn = __shfl_down(h, 1);
    if ((j & 1) == 0)
      STOREX(hseq + (size_t)(t + 1) * 2048 + ((b * 512 + u0 + j) >> 1), packf16(h, hn));
    if (hs) hs[((size_t)b * S + t) * HH + u0 + j] = h;
  }
}

// 16-unit WG (encoder L1): K-concat [Whh1|Wih1].
// LDS W[64][1032], H[8][1032], gat[8][68]. 32 WGs.
static __device__ __forceinline__ void lstm_l1(
    int wg, const float* __restrict__ gb, const f16* __restrict__ Wih,
    const f16* __restrict__ Whh, const u32* __restrict__ hin,
    u32* __restrict__ hseq, float* __restrict__ hs, int S) {
  extern __shared__ char smem[];
  f16 (*W)[1032] = (f16(*)[1032])smem;                      // 132,096 B
  f16 (*H)[1032] = (f16(*)[1032])(smem + 132096);           //  16,512 B
  float (*gat)[68] = (float(*)[68])(smem + 132096 + 16512); //   2,176 B
  const int tid = threadIdx.x;
  const int u0 = wg * 16;
  const int wave = tid >> 6, lane = tid & 63;
  const int rowa = lane & 15, kg = lane >> 4;

  // stage weights: LDS row r = g*16+i <-> global row g*512 + u0 + i
  for (int idx = tid; idx < 64 * 64; idx += 256) {
    int r = idx >> 6, ck = idx & 63;
    int g = r >> 4, i = r & 15;
    size_t grow = (size_t)(g * 512 + u0 + i) * 512;
    *(uint4*)&W[r][ck * 8]       = *(const uint4*)(Whh + grow + ck * 8);
    *(uint4*)&W[r][512 + ck * 8] = *(const uint4*)(Wih + grow + ck * 8);
  }
  // bias (scalar-phase threads only)
  float gbi = 0.f, gbf = 0.f, gbg = 0.f, gbo = 0.f;
  if (tid < 128) {
    int jj = tid & 15;
    gbi = gb[u0 + jj]; gbf = gb[512 + u0 + jj];
    gbg = gb[1024 + u0 + jj]; gbo = gb[1536 + u0 + jj];
  }
  __syncthreads();

  float c = 0.f;
  for (int t = 0; t < S; ++t) {
    // batched poll of self h1(t-1) AND upstream h0(t): 16 words in flight
    const u32* hbS = hseq + (size_t)t * 2048;
    const u32* hbU = hin + (size_t)(t + 1) * 2048;
    const u32* ptr[16];
    u32 vv[16];
#pragma unroll
    for (int k = 0; k < 8; ++k) {
      int idx = tid + k * 256;
      int r = idx >> 8, cu = idx & 255;
      ptr[k] = hbS + r * 256 + cu;
      ptr[k + 8] = hbU + r * 256 + cu;
    }
    poll_batch<16>(ptr, vv);
#pragma unroll
    for (int k = 0; k < 8; ++k) {
      int idx = tid + k * 256;
      int r = idx >> 8, cu = idx & 255;
      ((u32*)H)[r * 516 + cu] = vv[k];
      ((u32*)H)[r * 516 + 256 + cu] = vv[k + 8];
    }
    __syncthreads();  // B2

    f32x4 acc = {0.f, 0.f, 0.f, 0.f};
#pragma unroll
    for (int kf = 0; kf < 32; ++kf) {
      f16x8 af = {};
      if (rowa < 8) af = *(const f16x8*)&H[rowa][kf * 32 + kg * 8];
      f16x8 bf = *(const f16x8*)&W[wave * 16 + rowa][kf * 32 + kg * 8];
      acc = __builtin_amdgcn_mfma_f32_16x16x32_f16(af, bf, acc, 0, 0, 0);
    }
    if (kg < 2) {   // wave w = gate w; col = unit offset rowa
#pragma unroll
      for (int r = 0; r < 4; ++r) gat[kg * 4 + r][wave * 16 + rowa] = acc[r];
    }
    __syncthreads();  // B3

    if (tid < 128) {
      int b = tid >> 4, j = tid & 15;
      float gi = gat[b][j]      + gbi;
      float gf = gat[b][16 + j] + gbf;
      float gg = gat[b][32 + j] + gbg;
      float go = gat[b][48 + j] + gbo;
      c = sigm(gf) * c + sigm(gi) * ftanh(gg);
      float h = sigm(go) * ftanh(c);
      float hn = __shfl_down(h, 1);
      if ((j & 1) == 0)
        STOREX(hseq + (size_t)(t + 1) * 2048 + (b * 256 + ((u0 + j) >> 1)), packf16(h, hn));
      hs[((size_t)b * S + t) * HH + u0 + j] = h;
    }
  }
}

// all three LSTMs in one dispatch (64 WGs)
__global__ __launch_bounds__(256, 1) void k_lstm3(
    const float* xp0, const f16* Whh0, u32* hseq0,
    const float* b1, const f16* Wih1, const f16* Whh1, u32* hseq1, float* h1s,
    const float* xpd, const f16* Whhd, u32* hseqD, float* hds) {
  int g = blockIdx.x;
  if (g < 16)      lstm_16(g, xp0, Whh0, hseq0, nullptr, TT);
  else if (g < 48) lstm_l1(g - 16, b1, Wih1, Whh1, hseq0, hseq1, h1s, TT);
  else             lstm_16(g - 48, xpd, Whhd, hseqD, hds, UU1);
}

// ------------------------------ fused joint --------------------------------
__global__ __launch_bounds__(512) void k_joint(
    const float* __restrict__ pre_enc,   // [B*T][512]   (no bias)
    const float* __restrict__ pre_dec,   // [B*65][512]  (jb1 folded in)
    const f16* __restrict__ jW2,         // [1024][512] f16
    const float* __restrict__ jb2,
    float* __restrict__ out) {
  extern __shared__ char smem[];
  f16 (*Z)[520] = (f16(*)[520])smem;     // 133,120 B
  int tid = threadIdx.x;
  int m0 = blockIdx.x * 128;
  {
    int r = tid >> 2, q = tid & 3;
    int m = m0 + r;
    int bb = m / (TT * UU1);
    int rem = m % (TT * UU1);
    int t = rem / UU1, u = rem % UU1;
    const float* pe = pre_enc + ((size_t)bb * TT + t) * JJ + q * 128;
    const float* pd = pre_dec + ((size_t)bb * UU1 + u) * JJ + q * 128;
    for (int i = 0; i < 128; i += 8) {
      float4 e0 = *(const float4*)(pe + i);
      float4 e1 = *(const float4*)(pe + i + 4);
      float4 d0 = *(const float4*)(pd + i);
      float4 d1 = *(const float4*)(pd + i + 4);
      float z0 = ftanh(e0.x + d0.x), z1 = ftanh(e0.y + d0.y);
      float z2 = ftanh(e0.z + d0.z), z3 = ftanh(e0.w + d0.w);
      float z4 = ftanh(e1.x + d1.x), z5 = ftanh(e1.y + d1.y);
      float z6 = ftanh(e1.z + d1.z), z7 = ftanh(e1.w + d1.w);
      uint4 p; p.x = packf16(z0, z1); p.y = packf16(z2, z3);
      p.z = packf16(z4, z5); p.w = packf16(z6, z7);
      *(uint4*)&Z[r][q * 128 + i] = p;
    }
  }
  __syncthreads();
  int wave = tid >> 6, lane = tid & 63;
  int wm = wave >> 2, wn = wave & 3;
  int rowa = lane & 15, kg = lane >> 4;
  for (int ch = 0; ch < 4; ++ch) {       // 4 N-chunks of 256
    f32x4 acc[4][4] = {};
    int nb = ch * 256 + wn * 64;
    for (int kf = 0; kf < 16; ++kf) {
      f16x8 af[4], bf[4];
#pragma unroll
      for (int mt = 0; mt < 4; ++mt)
        af[mt] = *(const f16x8*)&Z[wm * 64 + mt * 16 + rowa][kf * 32 + kg * 8];
#pragma unroll
      for (int nt = 0; nt < 4; ++nt)
        bf[nt] = *(const f16x8*)(jW2 + (size_t)(nb + nt * 16 + rowa) * JJ + kf * 32 + kg * 8);
#pragma unroll
      for (int mt = 0; mt < 4; ++mt)
#pragma unroll
        for (int nt = 0; nt < 4; ++nt)
          acc[mt][nt] = __builtin_amdgcn_mfma_f32_16x16x32_f16(af[mt], bf[nt], acc[mt][nt], 0, 0, 0);
    }
#pragma unroll
    for (int nt = 0; nt < 4; ++nt) {
      int v = nb + nt * 16 + rowa;
      float bv = jb2[v];
#pragma unroll
      for (int mt = 0; mt < 4; ++mt)
#pragma unroll
        for (int r = 0; r < 4; ++r) {
          int m = m0 + wm * 64 + mt * 16 + kg * 4 + r;
          out[(size_t)m * VV + v] = acc[mt][nt][r] + bv;
        }
    }
  }
}

// ------------------------------- host side ---------------------------------
extern "C" void kernel_launch(void* const* d_in, const int* in_sizes, int n_in,
                              void* d_out, int out_size, void* d_ws, size_t ws_size,
                              hipStream_t stream) {
  const float* xs    = (const float*)d_in[0];
  const int*   ys    = (const int*)d_in[1];
  const float* Wih0  = (const float*)d_in[2];
  const float* Whh0  = (const float*)d_in[3];
  const float* b0    = (const float*)d_in[4];
  const float* Wih1  = (const float*)d_in[5];
  const float* Whh1  = (const float*)d_in[6];
  const float* b1    = (const float*)d_in[7];
  const float* encPW = (const float*)d_in[8];
  const float* encPb = (const float*)d_in[9];
  const float* embed = (const float*)d_in[10];
  const float* dWih  = (const float*)d_in[11];
  const float* dWhh  = (const float*)d_in[12];
  const float* db    = (const float*)d_in[13];
  const float* dPW   = (const float*)d_in[14];
  const float* dPb   = (const float*)d_in[15];
  const float* jW1   = (const float*)d_in[16];
  const float* jb1   = (const float*)d_in[17];
  const float* jW2   = (const float*)d_in[18];
  const float* jb2   = (const float*)d_in[19];
  float* out = (float*)d_out;

  char* base = (char*)d_ws;
  size_t off = 0;
  auto alc = [&](size_t bytes) -> char* {
    char* p = base + off;
    off = (off + bytes + 255) & ~(size_t)255;
    return p;
  };
  f16* Wih0h = (f16*)alc((size_t)2048 * 80 * 2);
  f16* Whh0h = (f16*)alc((size_t)2048 * 512 * 2);
  f16* Wih1h = (f16*)alc((size_t)2048 * 512 * 2);
  f16* Whh1h = (f16*)alc((size_t)2048 * 512 * 2);
  f16* dWihh = (f16*)alc((size_t)2048 * 512 * 2);
  f16* dWhhh = (f16*)alc((size_t)2048 * 512 * 2);
  f16* ePWh  = (f16*)alc((size_t)512 * 512 * 2);
  f16* dPWh  = (f16*)alc((size_t)512 * 512 * 2);
  f16* jW1h  = (f16*)alc((size_t)512 * 1024 * 2);
  f16* jW2h  = (f16*)alc((size_t)1024 * 512 * 2);
  float* e    = (float*)alc((size_t)520 * 512 * 4);
  float* xp0  = (float*)alc((size_t)2048 * 2048 * 4);
  float* xpd  = (float*)alc((size_t)520 * 2048 * 4);
  float* h1s  = (float*)alc((size_t)2048 * 512 * 4);
  float* hds  = (float*)alc((size_t)520 * 512 * 4);
  float* henc = (float*)alc((size_t)2048 * 512 * 4);
  float* hdec = (float*)alc((size_t)520 * 512 * 4);
  float* penc = (float*)alc((size_t)2048 * 512 * 4);
  float* pdec = (float*)alc((size_t)520 * 512 * 4);
  // sentinel-synced h sequences (contiguous; sizes are 256-multiples)
  u32* hseq0 = (u32*)alc((size_t)(TT + 1) * 2048 * 4);   // [257][2048]
  u32* hseq1 = (u32*)alc((size_t)(TT + 1) * 2048 * 4);   // [257][2048]
  u32* hseqD = (u32*)alc((size_t)(UU1 + 1) * 2048 * 4);  // [66][2048]
  if (off > ws_size) return;

  // 1) sentinel-fill hseq region, then zero slot 0 of each (h(-1) = 0)
  {
    int n = (int)(((TT + 1) * 2 + (UU1 + 1)) * 2048);
    k_fill<<<dim3((n + 255) / 256), dim3(256), 0, stream>>>(hseq0, n, SENT);
    k_zero<<<dim3(8), dim3(256), 0, stream>>>(hseq0, 2048);
    k_zero<<<dim3(8), dim3(256), 0, stream>>>(hseq1, 2048);
    k_zero<<<dim3(8), dim3(256), 0, stream>>>(hseqD, 2048);
  }
  // 2) cast weights to f16
  auto cast = [&](const float* s, f16* d, size_t n) {
    int n4 = (int)(n / 4);
    k_cast<<<dim3((n4 + 255) / 256), dim3(256), 0, stream>>>(s, d, n4);
  };
  cast(Wih0, Wih0h, (size_t)2048 * 80);
  cast(Whh0, Whh0h, (size_t)2048 * 512);
  cast(Wih1, Wih1h, (size_t)2048 * 512);
  cast(Whh1, Whh1h, (size_t)2048 * 512);
  cast(dWih, dWihh, (size_t)2048 * 512);
  cast(dWhh, dWhhh, (size_t)2048 * 512);
  cast(encPW, ePWh, (size_t)512 * 512);
  cast(dPW, dPWh, (size_t)512 * 512);
  cast(jW1, jW1h, (size_t)512 * 1024);
  cast(jW2, jW2h, (size_t)1024 * 512);

  // 3) embedding (decoder input)
  k_embed<<<dim3(520), dim3(128), 0, stream>>>(ys, embed, e);

  auto gemm = [&](const float* A, const f16* B, const float* bias, float* C,
                  int M, int N, int K, int lda, int ldb) {
    k_gemm<<<dim3(N / 128, (M + 127) / 128), dim3(256), 0, stream>>>(
        A, B, bias, C, M, N, K, lda, ldb);
  };

  // 4) input projections for enc L0 and decoder
  gemm(xs, Wih0h, b0, xp0, 2048, 2048, 80, 80, 80);
  gemm(e, dWihh, db, xpd, 520, 2048, 512, 512, 512);

  // 5) all three LSTMs, sentinel-pipelined, one dispatch (64 WGs)
  k_lstm3<<<dim3(64), dim3(256), 150784, stream>>>(
      xp0, Whh0h, hseq0,
      b1, Wih1h, Whh1h, hseq1, h1s,
      xpd, dWhhh, hseqD, hds);

  // 6) projections / joint pre-activations
  gemm(h1s, ePWh, encPb, henc, 2048, 512, 512, 512, 512);
  gemm(henc, jW1h, nullptr, penc, 2048, 512, 512, 512, 1024);
  gemm(hds, dPWh, dPb, hdec, 520, 512, 512, 512, 512);
  gemm(hdec, jW1h + 512, jb1, pdec, 520, 512, 512, 512, 1024);  // jb1 folded

  // 7) fused joint: z = tanh(penc+pdec) ; out = z @ jW2^T + jb2
  k_joint<<<dim3(1040), dim3(512), 133120, stream>>>(penc, pdec, jW2h, jb2, out);
}

// Round 6
// 1805.612 us; speedup vs baseline: 1.3228x; 1.3228x over previous
//
#include <hip/hip_runtime.h>

// ---------------------------------------------------------------------------
// Transducer forward (RNN-T). R5: R4 structure + s_sleep-throttled sentinel
// polls (LLC-contention fix) + merged weight-cast kernel.
//   WGs  0-15 : encoder L0 (256 steps), 32 units/WG, Whh0 in LDS
//   WGs 16-47 : encoder L1 (256 steps), 16 units/WG, [Whh1|Wih1] K=1024 in LDS
//   WGs 48-63 : decoder   (65 steps),  32 units/WG, dWhh in LDS
// h exchange: per-step write-once buffers pre-filled with sentinel
// 0xFFFFFFFF (f16 NaN pair; h in (-1,1) can never produce it). Consumers poll
// the data words directly; poll loop sleeps between iterations to avoid
// saturating the coherence point. RELAXED agent-scope atomics throughout.
// ---------------------------------------------------------------------------

typedef _Float16 f16;
typedef _Float16 f16x8 __attribute__((ext_vector_type(8)));
typedef float f32x4 __attribute__((ext_vector_type(4)));
using u32 = unsigned int;

#define BB   8
#define TT   256
#define UU1  65      // U+1
#define HH   512
#define G4   2048    // 4*H
#define PP   512
#define JJ   512
#define VV   1024
#define SENT 0xFFFFFFFFu

#define LOADX(p)     __hip_atomic_load((p), __ATOMIC_RELAXED, __HIP_MEMORY_SCOPE_AGENT)
#define STOREX(p, v) __hip_atomic_store((p), (v), __ATOMIC_RELAXED, __HIP_MEMORY_SCOPE_AGENT)

static __device__ __forceinline__ u32 packf16(float a, float b) {
  f16 ha = (f16)a, hb = (f16)b;
  unsigned short ua = __builtin_bit_cast(unsigned short, ha);
  unsigned short ub = __builtin_bit_cast(unsigned short, hb);
  return (u32)ua | ((u32)ub << 16);
}
static __device__ __forceinline__ float sigm(float x) {
  x = fminf(30.f, fmaxf(-30.f, x));
  return __builtin_amdgcn_rcpf(1.f + __expf(-x));
}
static __device__ __forceinline__ float ftanh(float x) {
  x = fminf(15.f, fmaxf(-15.f, x));
  float t = __expf(2.f * x);
  return (t - 1.f) * __builtin_amdgcn_rcpf(t + 1.f);
}

// ---------------------------- utility kernels ------------------------------
__global__ void k_zero(u32* __restrict__ p, int n) {
  int i = blockIdx.x * 256 + threadIdx.x;
  if (i < n) p[i] = 0u;
}
__global__ void k_fill(u32* __restrict__ p, int n, u32 v) {
  int i = blockIdx.x * 256 + threadIdx.x;
  if (i < n) p[i] = v;
}

// merged f32 -> f16 cast over 10 weight segments (one launch)
struct CastSeg { const float* s; f16* d; int n4; };
struct CastArgs { CastSeg seg[10]; };
__global__ void k_cast_all(CastArgs a, int total4) {
  int i = blockIdx.x * 256 + threadIdx.x;
  if (i >= total4) return;
  int k = 0, off = i;
  while (off >= a.seg[k].n4) { off -= a.seg[k].n4; ++k; }
  const float4 v = *(const float4*)(a.seg[k].s + (size_t)off * 4);
  uint2 p; p.x = packf16(v.x, v.y); p.y = packf16(v.z, v.w);
  *(uint2*)(a.seg[k].d + (size_t)off * 4) = p;
}

// e[row][0:512] = embed[ys_p[row]] ; row = b*65+u ; ys_p[b][0]=BOS=0
__global__ void k_embed(const int* __restrict__ ys, const float* __restrict__ emb,
                        float* __restrict__ e) {
  int row = blockIdx.x;                 // 0..519
  int b = row / UU1, u = row % UU1;
  int idx = (u == 0) ? 0 : ys[b * (UU1 - 1) + (u - 1)];
  const float4* s = (const float4*)(emb + (size_t)idx * HH);
  float4* d = (float4*)(e + (size_t)row * HH);
  d[threadIdx.x] = s[threadIdx.x];      // 128 threads x 16B = 2KB
}

// ------------------------------ generic GEMM -------------------------------
// C[M,N] = A[M,lda](f32) * B[N,ldb](f16)^T (+ bias[n]); MFMA f16 16x16x32.
__global__ __launch_bounds__(256) void k_gemm(
    const float* __restrict__ A, const f16* __restrict__ B,
    const float* __restrict__ bias, float* __restrict__ C,
    int M, int N, int K, int lda, int ldb) {
  __shared__ f16 As[128][72];
  __shared__ f16 Bs[128][72];
  int tid = threadIdx.x;
  int mb = blockIdx.y * 128, nb = blockIdx.x * 128;
  int wave = tid >> 6, lane = tid & 63;
  int wm = wave >> 1, wn = wave & 1;
  int rowa = lane & 15, kg = lane >> 4;
  f32x4 acc[4][4] = {};
  for (int k0 = 0; k0 < K; k0 += 64) {
    for (int idx = tid; idx < 2048; idx += 256) {
      int r = idx >> 4, cq = idx & 15;
      int gm = mb + r, gk = k0 + cq * 4;
      float4 v = make_float4(0.f, 0.f, 0.f, 0.f);
      if (gm < M && gk + 3 < K) v = *(const float4*)(A + (size_t)gm * lda + gk);
      uint2 p; p.x = packf16(v.x, v.y); p.y = packf16(v.z, v.w);
      *(uint2*)&As[r][cq * 4] = p;
    }
    for (int idx = tid; idx < 1024; idx += 256) {
      int r = idx >> 3, c8 = idx & 7;
      int gn = nb + r, gk = k0 + c8 * 8;
      uint4 v = make_uint4(0u, 0u, 0u, 0u);
      if (gn < N && gk + 7 < K) v = *(const uint4*)(B + (size_t)gn * ldb + gk);
      *(uint4*)&Bs[r][c8 * 8] = v;
    }
    __syncthreads();
#pragma unroll
    for (int kf = 0; kf < 2; ++kf) {
      f16x8 af[4], bf[4];
#pragma unroll
      for (int mt = 0; mt < 4; ++mt)
        af[mt] = *(const f16x8*)&As[wm * 64 + mt * 16 + rowa][kf * 32 + kg * 8];
#pragma unroll
      for (int nt = 0; nt < 4; ++nt)
        bf[nt] = *(const f16x8*)&Bs[wn * 64 + nt * 16 + rowa][kf * 32 + kg * 8];
#pragma unroll
      for (int mt = 0; mt < 4; ++mt)
#pragma unroll
        for (int nt = 0; nt < 4; ++nt)
          acc[mt][nt] = __builtin_amdgcn_mfma_f32_16x16x32_f16(af[mt], bf[nt], acc[mt][nt], 0, 0, 0);
    }
    __syncthreads();
  }
#pragma unroll
  for (int nt = 0; nt < 4; ++nt) {
    int gn = nb + wn * 64 + nt * 16 + rowa;
    float bv = bias ? bias[gn] : 0.f;
#pragma unroll
    for (int mt = 0; mt < 4; ++mt)
#pragma unroll
      for (int r = 0; r < 4; ++r) {
        int gm = mb + wm * 64 + mt * 16 + kg * 4 + r;
        if (gm < M) C[(size_t)gm * N + gn] = acc[mt][nt][r] + bv;
      }
  }
}

// --------------------- persistent LSTM, sentinel-synced --------------------
// Batched optimistic poll: fast first check (no sleep), then s_sleep-throttled
// re-check of laggard words only (all re-loads in flight per iteration).
template <int NW>
static __device__ __forceinline__ void poll_batch(const u32* const* p, u32* vv) {
#pragma unroll
  for (int k = 0; k < NW; ++k) vv[k] = LOADX(p[k]);   // all in flight
  int gd = 0;
  while (++gd < (1 << 18)) {
    bool any = false;
#pragma unroll
    for (int k = 0; k < NW; ++k) any = any | (vv[k] == SENT);
    if (!any) break;
    __builtin_amdgcn_s_sleep(4);    // ~256 cyc: throttle LLC request rate
#pragma unroll
    for (int k = 0; k < NW; ++k)
      if (vv[k] == SENT) vv[k] = LOADX(p[k]);
  }
}

// 32-unit WG (L0 / decoder): LDS W[128][520], H[8][520], gat[8][132].
static __device__ __forceinline__ void lstm_16(
    int wg, const float* __restrict__ xp, const f16* __restrict__ Whh,
    u32* __restrict__ hseq,   // [S+1][2048]; slot 0 zeroed, rest sentinel
    float* __restrict__ hs, int S) {
  extern __shared__ char smem[];
  f16 (*W)[520] = (f16(*)[520])smem;                       // 133,120 B
  f16 (*H)[520] = (f16(*)[520])(smem + 133120);            //   8,320 B
  float (*gat)[132] = (float(*)[132])(smem + 133120 + 8320);
  const int tid = threadIdx.x;
  const int u0 = wg * 32;
  const int wave = tid >> 6, lane = tid & 63;
  const int rowa = lane & 15, kg = lane >> 4;
  const int b = tid >> 5, j = tid & 31;

  // stage Whh slice: LDS row r = g*32+i <-> global row g*512 + u0 + i
  for (int idx = tid; idx < 128 * 64; idx += 256) {
    int r = idx >> 6, ck = idx & 63;
    int g = r >> 5, i = r & 31;
    uint4 v = *(const uint4*)(Whh + ((size_t)(g * 512 + u0 + i)) * 512 + ck * 8);
    *(uint4*)&W[r][ck * 8] = v;
  }
  __syncthreads();

  float c = 0.f;
  for (int t = 0; t < S; ++t) {
    // xp loads issued FIRST -> in flight during the poll
    size_t xpo = ((size_t)b * S + t) * (size_t)G4 + u0 + j;
    float xi = xp[xpo], xf = xp[xpo + 512], xg = xp[xpo + 1024], xo = xp[xpo + 1536];

    // batched poll+stage h(t-1) = hseq[t] (8 words/thread)
    const u32* hb = hseq + (size_t)t * 2048;
    const u32* ptr[8];
    u32 vv[8];
#pragma unroll
    for (int k = 0; k < 8; ++k) ptr[k] = hb + ((tid + k * 256) >> 8) * 256 + ((tid + k * 256) & 255);
    poll_batch<8>(ptr, vv);
#pragma unroll
    for (int k = 0; k < 8; ++k) {
      int idx = tid + k * 256;
      ((u32*)H)[(idx >> 8) * 260 + (idx & 255)] = vv[k];
    }
    __syncthreads();  // B2: H ready

    f32x4 acc0 = {0.f, 0.f, 0.f, 0.f}, acc1 = {0.f, 0.f, 0.f, 0.f};
#pragma unroll
    for (int kf = 0; kf < 16; ++kf) {
      f16x8 af = {};
      if (rowa < 8) af = *(const f16x8*)&H[rowa][kf * 32 + kg * 8];
      f16x8 b0 = *(const f16x8*)&W[wave * 32 + rowa][kf * 32 + kg * 8];
      f16x8 b1 = *(const f16x8*)&W[wave * 32 + 16 + rowa][kf * 32 + kg * 8];
      acc0 = __builtin_amdgcn_mfma_f32_16x16x32_f16(af, b0, acc0, 0, 0, 0);
      acc1 = __builtin_amdgcn_mfma_f32_16x16x32_f16(af, b1, acc1, 0, 0, 0);
    }
    if (kg < 2) {   // C rows 0..7 valid (batch)
#pragma unroll
      for (int r = 0; r < 4; ++r) {
        gat[kg * 4 + r][wave * 32 + rowa] = acc0[r];
        gat[kg * 4 + r][wave * 32 + 16 + rowa] = acc1[r];
      }
    }
    __syncthreads();  // B3: gat ready

    float gi = gat[b][j] + xi;
    float gf = gat[b][32 + j] + xf;
    float gg = gat[b][64 + j] + xg;
    float go = gat[b][96 + j] + xo;
    c = sigm(gf) * c + sigm(gi) * ftanh(gg);
    float h = sigm(go) * ftanh(c);

    float hn = __shfl_down(h, 1);
    if ((j & 1) == 0)
      STOREX(hseq + (size_t)(t + 1) * 2048 + ((b * 512 + u0 + j) >> 1), packf16(h, hn));
    if (hs) hs[((size_t)b * S + t) * HH + u0 + j] = h;
  }
}

// 16-unit WG (encoder L1): K-concat [Whh1|Wih1].
// LDS W[64][1032], H[8][1032], gat[8][68]. 32 WGs.
static __device__ __forceinline__ void lstm_l1(
    int wg, const float* __restrict__ gb, const f16* __restrict__ Wih,
    const f16* __restrict__ Whh, const u32* __restrict__ hin,
    u32* __restrict__ hseq, float* __restrict__ hs, int S) {
  extern __shared__ char smem[];
  f16 (*W)[1032] = (f16(*)[1032])smem;                      // 132,096 B
  f16 (*H)[1032] = (f16(*)[1032])(smem + 132096);           //  16,512 B
  float (*gat)[68] = (float(*)[68])(smem + 132096 + 16512); //   2,176 B
  const int tid = threadIdx.x;
  const int u0 = wg * 16;
  const int wave = tid >> 6, lane = tid & 63;
  const int rowa = lane & 15, kg = lane >> 4;

  // stage weights: LDS row r = g*16+i <-> global row g*512 + u0 + i
  for (int idx = tid; idx < 64 * 64; idx += 256) {
    int r = idx >> 6, ck = idx & 63;
    int g = r >> 4, i = r & 15;
    size_t grow = (size_t)(g * 512 + u0 + i) * 512;
    *(uint4*)&W[r][ck * 8]       = *(const uint4*)(Whh + grow + ck * 8);
    *(uint4*)&W[r][512 + ck * 8] = *(const uint4*)(Wih + grow + ck * 8);
  }
  // bias (scalar-phase threads only)
  float gbi = 0.f, gbf = 0.f, gbg = 0.f, gbo = 0.f;
  if (tid < 128) {
    int jj = tid & 15;
    gbi = gb[u0 + jj]; gbf = gb[512 + u0 + jj];
    gbg = gb[1024 + u0 + jj]; gbo = gb[1536 + u0 + jj];
  }
  __syncthreads();

  float c = 0.f;
  for (int t = 0; t < S; ++t) {
    // batched poll of self h1(t-1) AND upstream h0(t): 16 words in flight
    const u32* hbS = hseq + (size_t)t * 2048;
    const u32* hbU = hin + (size_t)(t + 1) * 2048;
    const u32* ptr[16];
    u32 vv[16];
#pragma unroll
    for (int k = 0; k < 8; ++k) {
      int idx = tid + k * 256;
      int r = idx >> 8, cu = idx & 255;
      ptr[k] = hbS + r * 256 + cu;
      ptr[k + 8] = hbU + r * 256 + cu;
    }
    poll_batch<16>(ptr, vv);
#pragma unroll
    for (int k = 0; k < 8; ++k) {
      int idx = tid + k * 256;
      int r = idx >> 8, cu = idx & 255;
      ((u32*)H)[r * 516 + cu] = vv[k];
      ((u32*)H)[r * 516 + 256 + cu] = vv[k + 8];
    }
    __syncthreads();  // B2

    f32x4 acc = {0.f, 0.f, 0.f, 0.f};
#pragma unroll
    for (int kf = 0; kf < 32; ++kf) {
      f16x8 af = {};
      if (rowa < 8) af = *(const f16x8*)&H[rowa][kf * 32 + kg * 8];
      f16x8 bf = *(const f16x8*)&W[wave * 16 + rowa][kf * 32 + kg * 8];
      acc = __builtin_amdgcn_mfma_f32_16x16x32_f16(af, bf, acc, 0, 0, 0);
    }
    if (kg < 2) {   // wave w = gate w; col = unit offset rowa
#pragma unroll
      for (int r = 0; r < 4; ++r) gat[kg * 4 + r][wave * 16 + rowa] = acc[r];
    }
    __syncthreads();  // B3

    if (tid < 128) {
      int b = tid >> 4, j = tid & 15;
      float gi = gat[b][j]      + gbi;
      float gf = gat[b][16 + j] + gbf;
      float gg = gat[b][32 + j] + gbg;
      float go = gat[b][48 + j] + gbo;
      c = sigm(gf) * c + sigm(gi) * ftanh(gg);
      float h = sigm(go) * ftanh(c);
      float hn = __shfl_down(h, 1);
      if ((j & 1) == 0)
        STOREX(hseq + (size_t)(t + 1) * 2048 + (b * 256 + ((u0 + j) >> 1)), packf16(h, hn));
      hs[((size_t)b * S + t) * HH + u0 + j] = h;
    }
  }
}

// all three LSTMs in one dispatch (64 WGs)
__global__ __launch_bounds__(256, 1) void k_lstm3(
    const float* xp0, const f16* Whh0, u32* hseq0,
    const float* b1, const f16* Wih1, const f16* Whh1, u32* hseq1, float* h1s,
    const float* xpd, const f16* Whhd, u32* hseqD, float* hds) {
  int g = blockIdx.x;
  if (g < 16)      lstm_16(g, xp0, Whh0, hseq0, nullptr, TT);
  else if (g < 48) lstm_l1(g - 16, b1, Wih1, Whh1, hseq0, hseq1, h1s, TT);
  else             lstm_16(g - 48, xpd, Whhd, hseqD, hds, UU1);
}

// ------------------------------ fused joint --------------------------------
__global__ __launch_bounds__(512) void k_joint(
    const float* __restrict__ pre_enc,   // [B*T][512]   (no bias)
    const float* __restrict__ pre_dec,   // [B*65][512]  (jb1 folded in)
    const f16* __restrict__ jW2,         // [1024][512] f16
    const float* __restrict__ jb2,
    float* __restrict__ out) {
  extern __shared__ char smem[];
  f16 (*Z)[520] = (f16(*)[520])smem;     // 133,120 B
  int tid = threadIdx.x;
  int m0 = blockIdx.x * 128;
  {
    int r = tid >> 2, q = tid & 3;
    int m = m0 + r;
    int bb = m / (TT * UU1);
    int rem = m % (TT * UU1);
    int t = rem / UU1, u = rem % UU1;
    const float* pe = pre_enc + ((size_t)bb * TT + t) * JJ + q * 128;
    const float* pd = pre_dec + ((size_t)bb * UU1 + u) * JJ + q * 128;
    for (int i = 0; i < 128; i += 8) {
      float4 e0 = *(const float4*)(pe + i);
      float4 e1 = *(const float4*)(pe + i + 4);
      float4 d0 = *(const float4*)(pd + i);
      float4 d1 = *(const float4*)(pd + i + 4);
      float z0 = ftanh(e0.x + d0.x), z1 = ftanh(e0.y + d0.y);
      float z2 = ftanh(e0.z + d0.z), z3 = ftanh(e0.w + d0.w);
      float z4 = ftanh(e1.x + d1.x), z5 = ftanh(e1.y + d1.y);
      float z6 = ftanh(e1.z + d1.z), z7 = ftanh(e1.w + d1.w);
      uint4 p; p.x = packf16(z0, z1); p.y = packf16(z2, z3);
      p.z = packf16(z4, z5); p.w = packf16(z6, z7);
      *(uint4*)&Z[r][q * 128 + i] = p;
    }
  }
  __syncthreads();
  int wave = tid >> 6, lane = tid & 63;
  int wm = wave >> 2, wn = wave & 3;
  int rowa = lane & 15, kg = lane >> 4;
  for (int ch = 0; ch < 4; ++ch) {       // 4 N-chunks of 256
    f32x4 acc[4][4] = {};
    int nb = ch * 256 + wn * 64;
    for (int kf = 0; kf < 16; ++kf) {
      f16x8 af[4], bf[4];
#pragma unroll
      for (int mt = 0; mt < 4; ++mt)
        af[mt] = *(const f16x8*)&Z[wm * 64 + mt * 16 + rowa][kf * 32 + kg * 8];
#pragma unroll
      for (int nt = 0; nt < 4; ++nt)
        bf[nt] = *(const f16x8*)(jW2 + (size_t)(nb + nt * 16 + rowa) * JJ + kf * 32 + kg * 8);
#pragma unroll
      for (int mt = 0; mt < 4; ++mt)
#pragma unroll
        for (int nt = 0; nt < 4; ++nt)
          acc[mt][nt] = __builtin_amdgcn_mfma_f32_16x16x32_f16(af[mt], bf[nt], acc[mt][nt], 0, 0, 0);
    }
#pragma unroll
    for (int nt = 0; nt < 4; ++nt) {
      int v = nb + nt * 16 + rowa;
      float bv = jb2[v];
#pragma unroll
      for (int mt = 0; mt < 4; ++mt)
#pragma unroll
        for (int r = 0; r < 4; ++r) {
          int m = m0 + wm * 64 + mt * 16 + kg * 4 + r;
          out[(size_t)m * VV + v] = acc[mt][nt][r] + bv;
        }
    }
  }
}

// ------------------------------- host side ---------------------------------
extern "C" void kernel_launch(void* const* d_in, const int* in_sizes, int n_in,
                              void* d_out, int out_size, void* d_ws, size_t ws_size,
                              hipStream_t stream) {
  const float* xs    = (const float*)d_in[0];
  const int*   ys    = (const int*)d_in[1];
  const float* Wih0  = (const float*)d_in[2];
  const float* Whh0  = (const float*)d_in[3];
  const float* b0    = (const float*)d_in[4];
  const float* Wih1  = (const float*)d_in[5];
  const float* Whh1  = (const float*)d_in[6];
  const float* b1    = (const float*)d_in[7];
  const float* encPW = (const float*)d_in[8];
  const float* encPb = (const float*)d_in[9];
  const float* embed = (const float*)d_in[10];
  const float* dWih  = (const float*)d_in[11];
  const float* dWhh  = (const float*)d_in[12];
  const float* db    = (const float*)d_in[13];
  const float* dPW   = (const float*)d_in[14];
  const float* dPb   = (const float*)d_in[15];
  const float* jW1   = (const float*)d_in[16];
  const float* jb1   = (const float*)d_in[17];
  const float* jW2   = (const float*)d_in[18];
  const float* jb2   = (const float*)d_in[19];
  float* out = (float*)d_out;

  char* base = (char*)d_ws;
  size_t off = 0;
  auto alc = [&](size_t bytes) -> char* {
    char* p = base + off;
    off = (off + bytes + 255) & ~(size_t)255;
    return p;
  };
  f16* Wih0h = (f16*)alc((size_t)2048 * 80 * 2);
  f16* Whh0h = (f16*)alc((size_t)2048 * 512 * 2);
  f16* Wih1h = (f16*)alc((size_t)2048 * 512 * 2);
  f16* Whh1h = (f16*)alc((size_t)2048 * 512 * 2);
  f16* dWihh = (f16*)alc((size_t)2048 * 512 * 2);
  f16* dWhhh = (f16*)alc((size_t)2048 * 512 * 2);
  f16* ePWh  = (f16*)alc((size_t)512 * 512 * 2);
  f16* dPWh  = (f16*)alc((size_t)512 * 512 * 2);
  f16* jW1h  = (f16*)alc((size_t)512 * 1024 * 2);
  f16* jW2h  = (f16*)alc((size_t)1024 * 512 * 2);
  float* e    = (float*)alc((size_t)520 * 512 * 4);
  float* xp0  = (float*)alc((size_t)2048 * 2048 * 4);
  float* xpd  = (float*)alc((size_t)520 * 2048 * 4);
  float* h1s  = (float*)alc((size_t)2048 * 512 * 4);
  float* hds  = (float*)alc((size_t)520 * 512 * 4);
  float* henc = (float*)alc((size_t)2048 * 512 * 4);
  float* hdec = (float*)alc((size_t)520 * 512 * 4);
  float* penc = (float*)alc((size_t)2048 * 512 * 4);
  float* pdec = (float*)alc((size_t)520 * 512 * 4);
  // sentinel-synced h sequences (contiguous; sizes are 256-multiples)
  u32* hseq0 = (u32*)alc((size_t)(TT + 1) * 2048 * 4);   // [257][2048]
  u32* hseq1 = (u32*)alc((size_t)(TT + 1) * 2048 * 4);   // [257][2048]
  u32* hseqD = (u32*)alc((size_t)(UU1 + 1) * 2048 * 4);  // [66][2048]
  if (off > ws_size) return;

  // 1) sentinel-fill hseq region, then zero slot 0 of each (h(-1) = 0)
  {
    int n = (int)(((TT + 1) * 2 + (UU1 + 1)) * 2048);
    k_fill<<<dim3((n + 255) / 256), dim3(256), 0, stream>>>(hseq0, n, SENT);
    k_zero<<<dim3(8), dim3(256), 0, stream>>>(hseq0, 2048);
    k_zero<<<dim3(8), dim3(256), 0, stream>>>(hseq1, 2048);
    k_zero<<<dim3(8), dim3(256), 0, stream>>>(hseqD, 2048);
  }
  // 2) cast all weights to f16 in ONE launch
  {
    CastArgs ca;
    auto seg = [&](int i, const float* s, f16* d, size_t n) {
      ca.seg[i].s = s; ca.seg[i].d = d; ca.seg[i].n4 = (int)(n / 4);
    };
    seg(0, Wih0, Wih0h, (size_t)2048 * 80);
    seg(1, Whh0, Whh0h, (size_t)2048 * 512);
    seg(2, Wih1, Wih1h, (size_t)2048 * 512);
    seg(3, Whh1, Whh1h, (size_t)2048 * 512);
    seg(4, dWih, dWihh, (size_t)2048 * 512);
    seg(5, dWhh, dWhhh, (size_t)2048 * 512);
    seg(6, encPW, ePWh, (size_t)512 * 512);
    seg(7, dPW, dPWh, (size_t)512 * 512);
    seg(8, jW1, jW1h, (size_t)512 * 1024);
    seg(9, jW2, jW2h, (size_t)1024 * 512);
    int total4 = 0;
    for (int i = 0; i < 10; ++i) total4 += ca.seg[i].n4;
    k_cast_all<<<dim3((total4 + 255) / 256), dim3(256), 0, stream>>>(ca, total4);
  }

  // 3) embedding (decoder input)
  k_embed<<<dim3(520), dim3(128), 0, stream>>>(ys, embed, e);

  auto gemm = [&](const float* A, const f16* B, const float* bias, float* C,
                  int M, int N, int K, int lda, int ldb) {
    k_gemm<<<dim3(N / 128, (M + 127) / 128), dim3(256), 0, stream>>>(
        A, B, bias, C, M, N, K, lda, ldb);
  };

  // 4) input projections for enc L0 and decoder
  gemm(xs, Wih0h, b0, xp0, 2048, 2048, 80, 80, 80);
  gemm(e, dWihh, db, xpd, 520, 2048, 512, 512, 512);

  // 5) all three LSTMs, sentinel-pipelined, one dispatch (64 WGs)
  k_lstm3<<<dim3(64), dim3(256), 150784, stream>>>(
      xp0, Whh0h, hseq0,
      b1, Wih1h, Whh1h, hseq1, h1s,
      xpd, dWhhh, hseqD, hds);

  // 6) projections / joint pre-activations
  gemm(h1s, ePWh, encPb, henc, 2048, 512, 512, 512, 512);
  gemm(henc, jW1h, nullptr, penc, 2048, 512, 512, 512, 1024);
  gemm(hds, dPWh, dPb, hdec, 520, 512, 512, 512, 512);
  gemm(hdec, jW1h + 512, jb1, pdec, 520, 512, 512, 512, 1024);  // jb1 folded

  // 7) fused joint: z = tanh(penc+pdec) ; out = z @ jW2^T + jb2
  k_joint<<<dim3(1040), dim3(512), 133120, stream>>>(penc, pdec, jW2h, jb2, out);
}

// Round 7
// 1617.831 us; speedup vs baseline: 1.4764x; 1.1161x over previous
//
#include <hip/hip_runtime.h>

// ---------------------------------------------------------------------------
// Transducer forward (RNN-T). R6: guard-then-verify sentinel polling
// (per-producer-WG guard words; ~200x less poll traffic), L1 split
// accumulators, 64-row joint tile (2 blocks/CU).
//   WGs  0-15 : encoder L0 (256 steps), 32 units/WG, Whh0 in LDS
//   WGs 16-47 : encoder L1 (256 steps), 16 units/WG, [Whh1|Wih1] K=1024 in LDS
//   WGs 48-63 : decoder   (65 steps),  32 units/WG, dWhh in LDS
// h exchange: per-step write-once buffers pre-filled with sentinel
// 0xFFFFFFFF (f16 NaN pair; h in (-1,1) can never produce it).
// ---------------------------------------------------------------------------

typedef _Float16 f16;
typedef _Float16 f16x8 __attribute__((ext_vector_type(8)));
typedef float f32x4 __attribute__((ext_vector_type(4)));
using u32 = unsigned int;

#define BB   8
#define TT   256
#define UU1  65      // U+1
#define HH   512
#define G4   2048    // 4*H
#define PP   512
#define JJ   512
#define VV   1024
#define SENT 0xFFFFFFFFu

#define LOADX(p)     __hip_atomic_load((p), __ATOMIC_RELAXED, __HIP_MEMORY_SCOPE_AGENT)
#define STOREX(p, v) __hip_atomic_store((p), (v), __ATOMIC_RELAXED, __HIP_MEMORY_SCOPE_AGENT)

static __device__ __forceinline__ u32 packf16(float a, float b) {
  f16 ha = (f16)a, hb = (f16)b;
  unsigned short ua = __builtin_bit_cast(unsigned short, ha);
  unsigned short ub = __builtin_bit_cast(unsigned short, hb);
  return (u32)ua | ((u32)ub << 16);
}
static __device__ __forceinline__ float sigm(float x) {
  x = fminf(30.f, fmaxf(-30.f, x));
  return __builtin_amdgcn_rcpf(1.f + __expf(-x));
}
static __device__ __forceinline__ float ftanh(float x) {
  x = fminf(15.f, fmaxf(-15.f, x));
  float t = __expf(2.f * x);
  return (t - 1.f) * __builtin_amdgcn_rcpf(t + 1.f);
}

// ---------------------------- utility kernels ------------------------------
__global__ void k_zero(u32* __restrict__ p, int n) {
  int i = blockIdx.x * 256 + threadIdx.x;
  if (i < n) p[i] = 0u;
}
__global__ void k_fill(u32* __restrict__ p, int n, u32 v) {
  int i = blockIdx.x * 256 + threadIdx.x;
  if (i < n) p[i] = v;
}

// merged f32 -> f16 cast over 10 weight segments (one launch)
struct CastSeg { const float* s; f16* d; int n4; };
struct CastArgs { CastSeg seg[10]; };
__global__ void k_cast_all(CastArgs a, int total4) {
  int i = blockIdx.x * 256 + threadIdx.x;
  if (i >= total4) return;
  int k = 0, off = i;
  while (off >= a.seg[k].n4) { off -= a.seg[k].n4; ++k; }
  const float4 v = *(const float4*)(a.seg[k].s + (size_t)off * 4);
  uint2 p; p.x = packf16(v.x, v.y); p.y = packf16(v.z, v.w);
  *(uint2*)(a.seg[k].d + (size_t)off * 4) = p;
}

// e[row][0:512] = embed[ys_p[row]] ; row = b*65+u ; ys_p[b][0]=BOS=0
__global__ void k_embed(const int* __restrict__ ys, const float* __restrict__ emb,
                        float* __restrict__ e) {
  int row = blockIdx.x;                 // 0..519
  int b = row / UU1, u = row % UU1;
  int idx = (u == 0) ? 0 : ys[b * (UU1 - 1) + (u - 1)];
  const float4* s = (const float4*)(emb + (size_t)idx * HH);
  float4* d = (float4*)(e + (size_t)row * HH);
  d[threadIdx.x] = s[threadIdx.x];      // 128 threads x 16B = 2KB
}

// ------------------------------ generic GEMM -------------------------------
// C[M,N] = A[M,lda](f32) * B[N,ldb](f16)^T (+ bias[n]); MFMA f16 16x16x32.
__global__ __launch_bounds__(256) void k_gemm(
    const float* __restrict__ A, const f16* __restrict__ B,
    const float* __restrict__ bias, float* __restrict__ C,
    int M, int N, int K, int lda, int ldb) {
  __shared__ f16 As[128][72];
  __shared__ f16 Bs[128][72];
  int tid = threadIdx.x;
  int mb = blockIdx.y * 128, nb = blockIdx.x * 128;
  int wave = tid >> 6, lane = tid & 63;
  int wm = wave >> 1, wn = wave & 1;
  int rowa = lane & 15, kg = lane >> 4;
  f32x4 acc[4][4] = {};
  for (int k0 = 0; k0 < K; k0 += 64) {
    for (int idx = tid; idx < 2048; idx += 256) {
      int r = idx >> 4, cq = idx & 15;
      int gm = mb + r, gk = k0 + cq * 4;
      float4 v = make_float4(0.f, 0.f, 0.f, 0.f);
      if (gm < M && gk + 3 < K) v = *(const float4*)(A + (size_t)gm * lda + gk);
      uint2 p; p.x = packf16(v.x, v.y); p.y = packf16(v.z, v.w);
      *(uint2*)&As[r][cq * 4] = p;
    }
    for (int idx = tid; idx < 1024; idx += 256) {
      int r = idx >> 3, c8 = idx & 7;
      int gn = nb + r, gk = k0 + c8 * 8;
      uint4 v = make_uint4(0u, 0u, 0u, 0u);
      if (gn < N && gk + 7 < K) v = *(const uint4*)(B + (size_t)gn * ldb + gk);
      *(uint4*)&Bs[r][c8 * 8] = v;
    }
    __syncthreads();
#pragma unroll
    for (int kf = 0; kf < 2; ++kf) {
      f16x8 af[4], bf[4];
#pragma unroll
      for (int mt = 0; mt < 4; ++mt)
        af[mt] = *(const f16x8*)&As[wm * 64 + mt * 16 + rowa][kf * 32 + kg * 8];
#pragma unroll
      for (int nt = 0; nt < 4; ++nt)
        bf[nt] = *(const f16x8*)&Bs[wn * 64 + nt * 16 + rowa][kf * 32 + kg * 8];
#pragma unroll
      for (int mt = 0; mt < 4; ++mt)
#pragma unroll
        for (int nt = 0; nt < 4; ++nt)
          acc[mt][nt] = __builtin_amdgcn_mfma_f32_16x16x32_f16(af[mt], bf[nt], acc[mt][nt], 0, 0, 0);
    }
    __syncthreads();
  }
#pragma unroll
  for (int nt = 0; nt < 4; ++nt) {
    int gn = nb + wn * 64 + nt * 16 + rowa;
    float bv = bias ? bias[gn] : 0.f;
#pragma unroll
    for (int mt = 0; mt < 4; ++mt)
#pragma unroll
      for (int r = 0; r < 4; ++r) {
        int gm = mb + wm * 64 + mt * 16 + kg * 4 + r;
        if (gm < M) C[(size_t)gm * N + gn] = acc[mt][nt][r] + bv;
      }
  }
}

// --------------------- persistent LSTM, sentinel-synced --------------------
// Verification pass: batched optimistic poll (all laggards in flight/iter).
template <int NW>
static __device__ __forceinline__ void poll_batch(const u32* const* p, u32* vv) {
#pragma unroll
  for (int k = 0; k < NW; ++k) vv[k] = LOADX(p[k]);   // all in flight
  int gd = 0;
  while (++gd < (1 << 18)) {
    bool any = false;
#pragma unroll
    for (int k = 0; k < NW; ++k) any = any | (vv[k] == SENT);
    if (!any) break;
    __builtin_amdgcn_s_sleep(4);
#pragma unroll
    for (int k = 0; k < NW; ++k)
      if (vv[k] == SENT) vv[k] = LOADX(p[k]);
  }
}
// Guard spin: 1 word, low-traffic fine-grained wait.
static __device__ __forceinline__ void guard_spin(const u32* gp) {
  u32 v = LOADX(gp);
  int gd = 0;
  while (v == SENT && ++gd < (1 << 18)) {
    __builtin_amdgcn_s_sleep(2);
    v = LOADX(gp);
  }
}

// 32-unit WG (L0 / decoder): LDS W[128][520], H[8][520], gat[8][132].
// Producer WG p (32-unit style) writes words {(b*512+p*32+j)>>1} -> guard p*16.
static __device__ __forceinline__ void lstm_16(
    int wg, const float* __restrict__ xp, const f16* __restrict__ Whh,
    u32* __restrict__ hseq,   // [S+1][2048]; slot 0 zeroed, rest sentinel
    float* __restrict__ hs, int S) {
  extern __shared__ char smem[];
  f16 (*W)[520] = (f16(*)[520])smem;                       // 133,120 B
  f16 (*H)[520] = (f16(*)[520])(smem + 133120);            //   8,320 B
  float (*gat)[132] = (float(*)[132])(smem + 133120 + 8320);
  const int tid = threadIdx.x;
  const int u0 = wg * 32;
  const int wave = tid >> 6, lane = tid & 63;
  const int rowa = lane & 15, kg = lane >> 4;
  const int b = tid >> 5, j = tid & 31;

  // stage Whh slice: LDS row r = g*32+i <-> global row g*512 + u0 + i
  for (int idx = tid; idx < 128 * 64; idx += 256) {
    int r = idx >> 6, ck = idx & 63;
    int g = r >> 5, i = r & 31;
    uint4 v = *(const uint4*)(Whh + ((size_t)(g * 512 + u0 + i)) * 512 + ck * 8);
    *(uint4*)&W[r][ck * 8] = v;
  }
  __syncthreads();

  float c = 0.f;
  for (int t = 0; t < S; ++t) {
    // xp loads issued FIRST -> in flight during the poll
    size_t xpo = ((size_t)b * S + t) * (size_t)G4 + u0 + j;
    float xi = xp[xpo], xf = xp[xpo + 512], xg = xp[xpo + 1024], xo = xp[xpo + 1536];

    const u32* hb = hseq + (size_t)t * 2048;
    // guard phase: 16 threads spin on 1 word per producer WG
    if (tid < 16) guard_spin(hb + tid * 16);
    __syncthreads();
    // verify + stage (usually a single full-BW pass)
    const u32* ptr[8];
    u32 vv[8];
#pragma unroll
    for (int k = 0; k < 8; ++k) ptr[k] = hb + ((tid + k * 256) >> 8) * 256 + ((tid + k * 256) & 255);
    poll_batch<8>(ptr, vv);
#pragma unroll
    for (int k = 0; k < 8; ++k) {
      int idx = tid + k * 256;
      ((u32*)H)[(idx >> 8) * 260 + (idx & 255)] = vv[k];
    }
    __syncthreads();  // B2: H ready

    f32x4 acc0 = {0.f, 0.f, 0.f, 0.f}, acc1 = {0.f, 0.f, 0.f, 0.f};
#pragma unroll
    for (int kf = 0; kf < 16; ++kf) {
      f16x8 af = {};
      if (rowa < 8) af = *(const f16x8*)&H[rowa][kf * 32 + kg * 8];
      f16x8 b0 = *(const f16x8*)&W[wave * 32 + rowa][kf * 32 + kg * 8];
      f16x8 b1 = *(const f16x8*)&W[wave * 32 + 16 + rowa][kf * 32 + kg * 8];
      acc0 = __builtin_amdgcn_mfma_f32_16x16x32_f16(af, b0, acc0, 0, 0, 0);
      acc1 = __builtin_amdgcn_mfma_f32_16x16x32_f16(af, b1, acc1, 0, 0, 0);
    }
    if (kg < 2) {   // C rows 0..7 valid (batch)
#pragma unroll
      for (int r = 0; r < 4; ++r) {
        gat[kg * 4 + r][wave * 32 + rowa] = acc0[r];
        gat[kg * 4 + r][wave * 32 + 16 + rowa] = acc1[r];
      }
    }
    __syncthreads();  // B3: gat ready

    float gi = gat[b][j] + xi;
    float gf = gat[b][32 + j] + xf;
    float gg = gat[b][64 + j] + xg;
    float go = gat[b][96 + j] + xo;
    c = sigm(gf) * c + sigm(gi) * ftanh(gg);
    float h = sigm(go) * ftanh(c);

    float hn = __shfl_down(h, 1);
    if ((j & 1) == 0)
      STOREX(hseq + (size_t)(t + 1) * 2048 + ((b * 512 + u0 + j) >> 1), packf16(h, hn));
    if (hs) hs[((size_t)b * S + t) * HH + u0 + j] = h;
  }
}

// 16-unit WG (encoder L1): K-concat [Whh1|Wih1].
// LDS W[64][1032], H[8][1032], gat[8][68]. 32 WGs.
// Self producers (16-unit WGs): guard p*8, p in [0,32). Upstream: guard p*16.
static __device__ __forceinline__ void lstm_l1(
    int wg, const float* __restrict__ gb, const f16* __restrict__ Wih,
    const f16* __restrict__ Whh, const u32* __restrict__ hin,
    u32* __restrict__ hseq, float* __restrict__ hs, int S) {
  extern __shared__ char smem[];
  f16 (*W)[1032] = (f16(*)[1032])smem;                      // 132,096 B
  f16 (*H)[1032] = (f16(*)[1032])(smem + 132096);           //  16,512 B
  float (*gat)[68] = (float(*)[68])(smem + 132096 + 16512); //   2,176 B
  const int tid = threadIdx.x;
  const int u0 = wg * 16;
  const int wave = tid >> 6, lane = tid & 63;
  const int rowa = lane & 15, kg = lane >> 4;

  // stage weights: LDS row r = g*16+i <-> global row g*512 + u0 + i
  for (int idx = tid; idx < 64 * 64; idx += 256) {
    int r = idx >> 6, ck = idx & 63;
    int g = r >> 4, i = r & 15;
    size_t grow = (size_t)(g * 512 + u0 + i) * 512;
    *(uint4*)&W[r][ck * 8]       = *(const uint4*)(Whh + grow + ck * 8);
    *(uint4*)&W[r][512 + ck * 8] = *(const uint4*)(Wih + grow + ck * 8);
  }
  // bias (scalar-phase threads only)
  float gbi = 0.f, gbf = 0.f, gbg = 0.f, gbo = 0.f;
  if (tid < 128) {
    int jj = tid & 15;
    gbi = gb[u0 + jj]; gbf = gb[512 + u0 + jj];
    gbg = gb[1024 + u0 + jj]; gbo = gb[1536 + u0 + jj];
  }
  __syncthreads();

  float c = 0.f;
  for (int t = 0; t < S; ++t) {
    const u32* hbS = hseq + (size_t)t * 2048;
    const u32* hbU = hin + (size_t)(t + 1) * 2048;
    // guard phase: 32 threads on self producers, 16 on upstream producers
    if (tid < 32)       guard_spin(hbS + tid * 8);
    else if (tid < 48)  guard_spin(hbU + (tid - 32) * 16);
    __syncthreads();
    // verify + stage (16 words in flight)
    const u32* ptr[16];
    u32 vv[16];
#pragma unroll
    for (int k = 0; k < 8; ++k) {
      int idx = tid + k * 256;
      int r = idx >> 8, cu = idx & 255;
      ptr[k] = hbS + r * 256 + cu;
      ptr[k + 8] = hbU + r * 256 + cu;
    }
    poll_batch<16>(ptr, vv);
#pragma unroll
    for (int k = 0; k < 8; ++k) {
      int idx = tid + k * 256;
      int r = idx >> 8, cu = idx & 255;
      ((u32*)H)[r * 516 + cu] = vv[k];
      ((u32*)H)[r * 516 + 256 + cu] = vv[k + 8];
    }
    __syncthreads();  // B2

    // split accumulators: two independent 16-long MFMA chains
    f32x4 accA = {0.f, 0.f, 0.f, 0.f}, accB = {0.f, 0.f, 0.f, 0.f};
#pragma unroll
    for (int kf = 0; kf < 16; ++kf) {
      f16x8 afA = {}, afB = {};
      if (rowa < 8) {
        afA = *(const f16x8*)&H[rowa][kf * 32 + kg * 8];
        afB = *(const f16x8*)&H[rowa][(kf + 16) * 32 + kg * 8];
      }
      f16x8 bfA = *(const f16x8*)&W[wave * 16 + rowa][kf * 32 + kg * 8];
      f16x8 bfB = *(const f16x8*)&W[wave * 16 + rowa][(kf + 16) * 32 + kg * 8];
      accA = __builtin_amdgcn_mfma_f32_16x16x32_f16(afA, bfA, accA, 0, 0, 0);
      accB = __builtin_amdgcn_mfma_f32_16x16x32_f16(afB, bfB, accB, 0, 0, 0);
    }
    if (kg < 2) {   // wave w = gate w; col = unit offset rowa
#pragma unroll
      for (int r = 0; r < 4; ++r) gat[kg * 4 + r][wave * 16 + rowa] = accA[r] + accB[r];
    }
    __syncthreads();  // B3

    if (tid < 128) {
      int b = tid >> 4, j = tid & 15;
      float gi = gat[b][j]      + gbi;
      float gf = gat[b][16 + j] + gbf;
      float gg = gat[b][32 + j] + gbg;
      float go = gat[b][48 + j] + gbo;
      c = sigm(gf) * c + sigm(gi) * ftanh(gg);
      float h = sigm(go) * ftanh(c);
      float hn = __shfl_down(h, 1);
      if ((j & 1) == 0)
        STOREX(hseq + (size_t)(t + 1) * 2048 + (b * 256 + ((u0 + j) >> 1)), packf16(h, hn));
      hs[((size_t)b * S + t) * HH + u0 + j] = h;
    }
  }
}

// all three LSTMs in one dispatch (64 WGs)
__global__ __launch_bounds__(256, 1) void k_lstm3(
    const float* xp0, const f16* Whh0, u32* hseq0,
    const float* b1, const f16* Wih1, const f16* Whh1, u32* hseq1, float* h1s,
    const float* xpd, const f16* Whhd, u32* hseqD, float* hds) {
  int g = blockIdx.x;
  if (g < 16)      lstm_16(g, xp0, Whh0, hseq0, nullptr, TT);
  else if (g < 48) lstm_l1(g - 16, b1, Wih1, Whh1, hseq0, hseq1, h1s, TT);
  else             lstm_16(g - 48, xpd, Whhd, hseqD, hds, UU1);
}

// ------------------------------ fused joint --------------------------------
// 64-row M-tile (66,560 B LDS -> 2 blocks/CU), 512 threads, grid 2080.
__global__ __launch_bounds__(512) void k_joint(
    const float* __restrict__ pre_enc,   // [B*T][512]   (no bias)
    const float* __restrict__ pre_dec,   // [B*65][512]  (jb1 folded in)
    const f16* __restrict__ jW2,         // [1024][512] f16
    const float* __restrict__ jb2,
    float* __restrict__ out) {
  extern __shared__ char smem[];
  f16 (*Z)[520] = (f16(*)[520])smem;     // 64 x 1040 B = 66,560 B
  int tid = threadIdx.x;
  int m0 = blockIdx.x * 64;
  {
    int r = tid >> 3, q = tid & 7;       // 8 threads per row, 64 cols each
    int m = m0 + r;
    int bb = m / (TT * UU1);
    int rem = m % (TT * UU1);
    int t = rem / UU1, u = rem % UU1;
    const float* pe = pre_enc + ((size_t)bb * TT + t) * JJ + q * 64;
    const float* pd = pre_dec + ((size_t)bb * UU1 + u) * JJ + q * 64;
    for (int i = 0; i < 64; i += 8) {
      float4 e0 = *(const float4*)(pe + i);
      float4 e1 = *(const float4*)(pe + i + 4);
      float4 d0 = *(const float4*)(pd + i);
      float4 d1 = *(const float4*)(pd + i + 4);
      float z0 = ftanh(e0.x + d0.x), z1 = ftanh(e0.y + d0.y);
      float z2 = ftanh(e0.z + d0.z), z3 = ftanh(e0.w + d0.w);
      float z4 = ftanh(e1.x + d1.x), z5 = ftanh(e1.y + d1.y);
      float z6 = ftanh(e1.z + d1.z), z7 = ftanh(e1.w + d1.w);
      uint4 p; p.x = packf16(z0, z1); p.y = packf16(z2, z3);
      p.z = packf16(z4, z5); p.w = packf16(z6, z7);
      *(uint4*)&Z[r][q * 64 + i] = p;
    }
  }
  __syncthreads();
  int wave = tid >> 6, lane = tid & 63;
  int wm = wave >> 2, wn = wave & 3;     // 2 x 4 waves over 64 x 256
  int rowa = lane & 15, kg = lane >> 4;
  for (int ch = 0; ch < 4; ++ch) {       // 4 N-chunks of 256
    f32x4 acc[2][4] = {};
    int nb = ch * 256 + wn * 64;
    for (int kf = 0; kf < 16; ++kf) {
      f16x8 af[2], bf[4];
#pragma unroll
      for (int mt = 0; mt < 2; ++mt)
        af[mt] = *(const f16x8*)&Z[wm * 32 + mt * 16 + rowa][kf * 32 + kg * 8];
#pragma unroll
      for (int nt = 0; nt < 4; ++nt)
        bf[nt] = *(const f16x8*)(jW2 + (size_t)(nb + nt * 16 + rowa) * JJ + kf * 32 + kg * 8);
#pragma unroll
      for (int mt = 0; mt < 2; ++mt)
#pragma unroll
        for (int nt = 0; nt < 4; ++nt)
          acc[mt][nt] = __builtin_amdgcn_mfma_f32_16x16x32_f16(af[mt], bf[nt], acc[mt][nt], 0, 0, 0);
    }
#pragma unroll
    for (int nt = 0; nt < 4; ++nt) {
      int v = nb + nt * 16 + rowa;
      float bv = jb2[v];
#pragma unroll
      for (int mt = 0; mt < 2; ++mt)
#pragma unroll
        for (int r = 0; r < 4; ++r) {
          int m = m0 + wm * 32 + mt * 16 + kg * 4 + r;
          out[(size_t)m * VV + v] = acc[mt][nt][r] + bv;
        }
    }
  }
}

// ------------------------------- host side ---------------------------------
extern "C" void kernel_launch(void* const* d_in, const int* in_sizes, int n_in,
                              void* d_out, int out_size, void* d_ws, size_t ws_size,
                              hipStream_t stream) {
  const float* xs    = (const float*)d_in[0];
  const int*   ys    = (const int*)d_in[1];
  const float* Wih0  = (const float*)d_in[2];
  const float* Whh0  = (const float*)d_in[3];
  const float* b0    = (const float*)d_in[4];
  const float* Wih1  = (const float*)d_in[5];
  const float* Whh1  = (const float*)d_in[6];
  const float* b1    = (const float*)d_in[7];
  const float* encPW = (const float*)d_in[8];
  const float* encPb = (const float*)d_in[9];
  const float* embed = (const float*)d_in[10];
  const float* dWih  = (const float*)d_in[11];
  const float* dWhh  = (const float*)d_in[12];
  const float* db    = (const float*)d_in[13];
  const float* dPW   = (const float*)d_in[14];
  const float* dPb   = (const float*)d_in[15];
  const float* jW1   = (const float*)d_in[16];
  const float* jb1   = (const float*)d_in[17];
  const float* jW2   = (const float*)d_in[18];
  const float* jb2   = (const float*)d_in[19];
  float* out = (float*)d_out;

  char* base = (char*)d_ws;
  size_t off = 0;
  auto alc = [&](size_t bytes) -> char* {
    char* p = base + off;
    off = (off + bytes + 255) & ~(size_t)255;
    return p;
  };
  f16* Wih0h = (f16*)alc((size_t)2048 * 80 * 2);
  f16* Whh0h = (f16*)alc((size_t)2048 * 512 * 2);
  f16* Wih1h = (f16*)alc((size_t)2048 * 512 * 2);
  f16* Whh1h = (f16*)alc((size_t)2048 * 512 * 2);
  f16* dWihh = (f16*)alc((size_t)2048 * 512 * 2);
  f16* dWhhh = (f16*)alc((size_t)2048 * 512 * 2);
  f16* ePWh  = (f16*)alc((size_t)512 * 512 * 2);
  f16* dPWh  = (f16*)alc((size_t)512 * 512 * 2);
  f16* jW1h  = (f16*)alc((size_t)512 * 1024 * 2);
  f16* jW2h  = (f16*)alc((size_t)1024 * 512 * 2);
  float* e    = (float*)alc((size_t)520 * 512 * 4);
  float* xp0  = (float*)alc((size_t)2048 * 2048 * 4);
  float* xpd  = (float*)alc((size_t)520 * 2048 * 4);
  float* h1s  = (float*)alc((size_t)2048 * 512 * 4);
  float* hds  = (float*)alc((size_t)520 * 512 * 4);
  float* henc = (float*)alc((size_t)2048 * 512 * 4);
  float* hdec = (float*)alc((size_t)520 * 512 * 4);
  float* penc = (float*)alc((size_t)2048 * 512 * 4);
  float* pdec = (float*)alc((size_t)520 * 512 * 4);
  // sentinel-synced h sequences (contiguous; sizes are 256-multiples)
  u32* hseq0 = (u32*)alc((size_t)(TT + 1) * 2048 * 4);   // [257][2048]
  u32* hseq1 = (u32*)alc((size_t)(TT + 1) * 2048 * 4);   // [257][2048]
  u32* hseqD = (u32*)alc((size_t)(UU1 + 1) * 2048 * 4);  // [66][2048]
  if (off > ws_size) return;

  // 1) sentinel-fill hseq region, then zero slot 0 of each (h(-1) = 0)
  {
    int n = (int)(((TT + 1) * 2 + (UU1 + 1)) * 2048);
    k_fill<<<dim3((n + 255) / 256), dim3(256), 0, stream>>>(hseq0, n, SENT);
    k_zero<<<dim3(8), dim3(256), 0, stream>>>(hseq0, 2048);
    k_zero<<<dim3(8), dim3(256), 0, stream>>>(hseq1, 2048);
    k_zero<<<dim3(8), dim3(256), 0, stream>>>(hseqD, 2048);
  }
  // 2) cast all weights to f16 in ONE launch
  {
    CastArgs ca;
    auto seg = [&](int i, const float* s, f16* d, size_t n) {
      ca.seg[i].s = s; ca.seg[i].d = d; ca.seg[i].n4 = (int)(n / 4);
    };
    seg(0, Wih0, Wih0h, (size_t)2048 * 80);
    seg(1, Whh0, Whh0h, (size_t)2048 * 512);
    seg(2, Wih1, Wih1h, (size_t)2048 * 512);
    seg(3, Whh1, Whh1h, (size_t)2048 * 512);
    seg(4, dWih, dWihh, (size_t)2048 * 512);
    seg(5, dWhh, dWhhh, (size_t)2048 * 512);
    seg(6, encPW, ePWh, (size_t)512 * 512);
    seg(7, dPW, dPWh, (size_t)512 * 512);
    seg(8, jW1, jW1h, (size_t)512 * 1024);
    seg(9, jW2, jW2h, (size_t)1024 * 512);
    int total4 = 0;
    for (int i = 0; i < 10; ++i) total4 += ca.seg[i].n4;
    k_cast_all<<<dim3((total4 + 255) / 256), dim3(256), 0, stream>>>(ca, total4);
  }

  // 3) embedding (decoder input)
  k_embed<<<dim3(520), dim3(128), 0, stream>>>(ys, embed, e);

  auto gemm = [&](const float* A, const f16* B, const float* bias, float* C,
                  int M, int N, int K, int lda, int ldb) {
    k_gemm<<<dim3(N / 128, (M + 127) / 128), dim3(256), 0, stream>>>(
        A, B, bias, C, M, N, K, lda, ldb);
  };

  // 4) input projections for enc L0 and decoder
  gemm(xs, Wih0h, b0, xp0, 2048, 2048, 80, 80, 80);
  gemm(e, dWihh, db, xpd, 520, 2048, 512, 512, 512);

  // 5) all three LSTMs, sentinel-pipelined, one dispatch (64 WGs)
  k_lstm3<<<dim3(64), dim3(256), 150784, stream>>>(
      xp0, Whh0h, hseq0,
      b1, Wih1h, Whh1h, hseq1, h1s,
      xpd, dWhhh, hseqD, hds);

  // 6) projections / joint pre-activations
  gemm(h1s, ePWh, encPb, henc, 2048, 512, 512, 512, 512);
  gemm(henc, jW1h, nullptr, penc, 2048, 512, 512, 512, 1024);
  gemm(hds, dPWh, dPb, hdec, 520, 512, 512, 512, 512);
  gemm(hdec, jW1h + 512, jb1, pdec, 520, 512, 512, 512, 1024);  // jb1 folded

  // 7) fused joint: z = tanh(penc+pdec) ; out = z @ jW2^T + jb2
  k_joint<<<dim3(2080), dim3(512), 66560, stream>>>(penc, pdec, jW2h, jb2, out);
}

// Round 9
// 1589.097 us; speedup vs baseline: 1.5031x; 1.0181x over previous
//
#include <hip/hip_runtime.h>

// ---------------------------------------------------------------------------
// Transducer forward (RNN-T). R7b (compile fix of R7):
//  - LSTM: wave-local gate ownership (each wave computes all 4 gates of its
//    own units) -> B3 barrier removed; 2 barriers/step.
//  - Joint: swapped MFMA operands -> per-lane f32x4 nontemporal stores.
//  - k_init single launch for sentinel init.
// Sync: per-step write-once sentinel buffers (0xFFFFFFFF = f16 NaN pair),
// guard-then-verify polling, RELAXED agent-scope atomics.
// ---------------------------------------------------------------------------

typedef _Float16 f16;
typedef _Float16 f16x8 __attribute__((ext_vector_type(8)));
typedef float f32x4 __attribute__((ext_vector_type(4)));
using u32 = unsigned int;

#define BB   8
#define TT   256
#define UU1  65      // U+1
#define HH   512
#define G4   2048    // 4*H
#define PP   512
#define JJ   512
#define VV   1024
#define SENT 0xFFFFFFFFu

#define LOADX(p)     __hip_atomic_load((p), __ATOMIC_RELAXED, __HIP_MEMORY_SCOPE_AGENT)
#define STOREX(p, v) __hip_atomic_store((p), (v), __ATOMIC_RELAXED, __HIP_MEMORY_SCOPE_AGENT)

static __device__ __forceinline__ u32 packf16(float a, float b) {
  f16 ha = (f16)a, hb = (f16)b;
  unsigned short ua = __builtin_bit_cast(unsigned short, ha);
  unsigned short ub = __builtin_bit_cast(unsigned short, hb);
  return (u32)ua | ((u32)ub << 16);
}
static __device__ __forceinline__ float sigm(float x) {
  x = fminf(30.f, fmaxf(-30.f, x));
  return __builtin_amdgcn_rcpf(1.f + __expf(-x));
}
static __device__ __forceinline__ float ftanh(float x) {
  x = fminf(15.f, fmaxf(-15.f, x));
  float t = __expf(2.f * x);
  return (t - 1.f) * __builtin_amdgcn_rcpf(t + 1.f);
}

// ---------------------------- utility kernels ------------------------------
// sentinel-fill the whole hseq region; zero slot 0 of each sequence
__global__ void k_init(u32* __restrict__ p, int n, int z1, int z2) {
  int i = blockIdx.x * 256 + threadIdx.x;
  if (i >= n) return;
  bool z = (i < 2048) | ((u32)(i - z1) < 2048u) | ((u32)(i - z2) < 2048u);
  p[i] = z ? 0u : SENT;
}

// merged f32 -> f16 cast over 10 weight segments (one launch)
struct CastSeg { const float* s; f16* d; int n4; };
struct CastArgs { CastSeg seg[10]; };
__global__ void k_cast_all(CastArgs a, int total4) {
  int i = blockIdx.x * 256 + threadIdx.x;
  if (i >= total4) return;
  int k = 0, off = i;
  while (off >= a.seg[k].n4) { off -= a.seg[k].n4; ++k; }
  const float4 v = *(const float4*)(a.seg[k].s + (size_t)off * 4);
  uint2 p; p.x = packf16(v.x, v.y); p.y = packf16(v.z, v.w);
  *(uint2*)(a.seg[k].d + (size_t)off * 4) = p;
}

// e[row][0:512] = embed[ys_p[row]] ; row = b*65+u ; ys_p[b][0]=BOS=0
__global__ void k_embed(const int* __restrict__ ys, const float* __restrict__ emb,
                        float* __restrict__ e) {
  int row = blockIdx.x;                 // 0..519
  int b = row / UU1, u = row % UU1;
  int idx = (u == 0) ? 0 : ys[b * (UU1 - 1) + (u - 1)];
  const float4* s = (const float4*)(emb + (size_t)idx * HH);
  float4* d = (float4*)(e + (size_t)row * HH);
  d[threadIdx.x] = s[threadIdx.x];      // 128 threads x 16B = 2KB
}

// ------------------------------ generic GEMM -------------------------------
// C[M,N] = A[M,lda](f32) * B[N,ldb](f16)^T (+ bias[n]); MFMA f16 16x16x32.
__global__ __launch_bounds__(256) void k_gemm(
    const float* __restrict__ A, const f16* __restrict__ B,
    const float* __restrict__ bias, float* __restrict__ C,
    int M, int N, int K, int lda, int ldb) {
  __shared__ f16 As[128][72];
  __shared__ f16 Bs[128][72];
  int tid = threadIdx.x;
  int mb = blockIdx.y * 128, nb = blockIdx.x * 128;
  int wave = tid >> 6, lane = tid & 63;
  int wm = wave >> 1, wn = wave & 1;
  int rowa = lane & 15, kg = lane >> 4;
  f32x4 acc[4][4] = {};
  for (int k0 = 0; k0 < K; k0 += 64) {
    for (int idx = tid; idx < 2048; idx += 256) {
      int r = idx >> 4, cq = idx & 15;
      int gm = mb + r, gk = k0 + cq * 4;
      float4 v = make_float4(0.f, 0.f, 0.f, 0.f);
      if (gm < M && gk + 3 < K) v = *(const float4*)(A + (size_t)gm * lda + gk);
      uint2 p; p.x = packf16(v.x, v.y); p.y = packf16(v.z, v.w);
      *(uint2*)&As[r][cq * 4] = p;
    }
    for (int idx = tid; idx < 1024; idx += 256) {
      int r = idx >> 3, c8 = idx & 7;
      int gn = nb + r, gk = k0 + c8 * 8;
      uint4 v = make_uint4(0u, 0u, 0u, 0u);
      if (gn < N && gk + 7 < K) v = *(const uint4*)(B + (size_t)gn * ldb + gk);
      *(uint4*)&Bs[r][c8 * 8] = v;
    }
    __syncthreads();
#pragma unroll
    for (int kf = 0; kf < 2; ++kf) {
      f16x8 af[4], bf[4];
#pragma unroll
      for (int mt = 0; mt < 4; ++mt)
        af[mt] = *(const f16x8*)&As[wm * 64 + mt * 16 + rowa][kf * 32 + kg * 8];
#pragma unroll
      for (int nt = 0; nt < 4; ++nt)
        bf[nt] = *(const f16x8*)&Bs[wn * 64 + nt * 16 + rowa][kf * 32 + kg * 8];
#pragma unroll
      for (int mt = 0; mt < 4; ++mt)
#pragma unroll
        for (int nt = 0; nt < 4; ++nt)
          acc[mt][nt] = __builtin_amdgcn_mfma_f32_16x16x32_f16(af[mt], bf[nt], acc[mt][nt], 0, 0, 0);
    }
    __syncthreads();
  }
#pragma unroll
  for (int nt = 0; nt < 4; ++nt) {
    int gn = nb + wn * 64 + nt * 16 + rowa;
    float bv = bias ? bias[gn] : 0.f;
#pragma unroll
    for (int mt = 0; mt < 4; ++mt)
#pragma unroll
      for (int r = 0; r < 4; ++r) {
        int gm = mb + wm * 64 + mt * 16 + kg * 4 + r;
        if (gm < M) C[(size_t)gm * N + gn] = acc[mt][nt][r] + bv;
      }
  }
}

// --------------------- persistent LSTM, sentinel-synced --------------------
template <int NW>
static __device__ __forceinline__ void poll_batch(const u32* const* p, u32* vv) {
#pragma unroll
  for (int k = 0; k < NW; ++k) vv[k] = LOADX(p[k]);   // all in flight
  int gd = 0;
  while (++gd < (1 << 18)) {
    bool any = false;
#pragma unroll
    for (int k = 0; k < NW; ++k) any = any | (vv[k] == SENT);
    if (!any) break;
    __builtin_amdgcn_s_sleep(4);
#pragma unroll
    for (int k = 0; k < NW; ++k)
      if (vv[k] == SENT) vv[k] = LOADX(p[k]);
  }
}
static __device__ __forceinline__ void guard_spin(const u32* gp) {
  u32 v = LOADX(gp);
  int gd = 0;
  while (v == SENT && ++gd < (1 << 18)) {
    __builtin_amdgcn_s_sleep(2);
    v = LOADX(gp);
  }
}

// 32-unit WG (L0 / decoder). Wave w owns units [w*8, w*8+8), ALL 4 gates.
// LDS W row r = w*32 + g*8 + ju  <->  global gate row g*512 + u0 + w*8 + ju.
// Scalar phase is wave-local (no B3 barrier).
static __device__ __forceinline__ void lstm_16(
    int wg, const float* __restrict__ xp, const f16* __restrict__ Whh,
    u32* __restrict__ hseq,   // [S+1][2048]; slot 0 zeroed, rest sentinel
    float* __restrict__ hs, int S) {
  extern __shared__ char smem[];
  f16 (*W)[520] = (f16(*)[520])smem;                       // 133,120 B
  f16 (*H)[520] = (f16(*)[520])(smem + 133120);            //   8,320 B
  float (*gat)[8][36] = (float(*)[8][36])(smem + 133120 + 8320); // 4,608 B
  const int tid = threadIdx.x;
  const int u0 = wg * 32;
  const int wave = tid >> 6, lane = tid & 63;
  const int rowa = lane & 15, kg = lane >> 4;
  const int b = lane >> 3, ju = lane & 7;          // scalar-phase mapping
  const int uglob = u0 + wave * 8 + ju;

  // stage Whh slice: LDS row r = w*32 + g*8 + ju
  for (int idx = tid; idx < 128 * 64; idx += 256) {
    int r = idx >> 6, ck = idx & 63;
    int w = r >> 5, g = (r >> 3) & 3, u = r & 7;
    uint4 v = *(const uint4*)(Whh + ((size_t)(g * 512 + u0 + w * 8 + u)) * 512 + ck * 8);
    *(uint4*)&W[r][ck * 8] = v;
  }
  __syncthreads();

  float c = 0.f;
  for (int t = 0; t < S; ++t) {
    const u32* hb = hseq + (size_t)t * 2048;
    // guard phase: 16 threads spin on 1 word per producer WG
    if (tid < 16) guard_spin(hb + tid * 16);
    __syncthreads();   // also protects H from next-step overwrite

    // xp loads in flight during verify
    size_t xpo = ((size_t)b * S + t) * (size_t)G4 + uglob;
    float xi = xp[xpo], xf = xp[xpo + 512], xg = xp[xpo + 1024], xo = xp[xpo + 1536];

    // verify + stage h(t-1)
    const u32* ptr[8];
    u32 vv[8];
#pragma unroll
    for (int k = 0; k < 8; ++k) ptr[k] = hb + ((tid + k * 256) >> 8) * 256 + ((tid + k * 256) & 255);
    poll_batch<8>(ptr, vv);
#pragma unroll
    for (int k = 0; k < 8; ++k) {
      int idx = tid + k * 256;
      ((u32*)H)[(idx >> 8) * 260 + (idx & 255)] = vv[k];
    }
    __syncthreads();  // B2: H ready

    f32x4 acc0 = {0.f, 0.f, 0.f, 0.f}, acc1 = {0.f, 0.f, 0.f, 0.f};
#pragma unroll
    for (int kf = 0; kf < 16; ++kf) {
      f16x8 af = {};
      if (rowa < 8) af = *(const f16x8*)&H[rowa][kf * 32 + kg * 8];
      f16x8 b0 = *(const f16x8*)&W[wave * 32 + rowa][kf * 32 + kg * 8];
      f16x8 b1 = *(const f16x8*)&W[wave * 32 + 16 + rowa][kf * 32 + kg * 8];
      acc0 = __builtin_amdgcn_mfma_f32_16x16x32_f16(af, b0, acc0, 0, 0, 0);
      acc1 = __builtin_amdgcn_mfma_f32_16x16x32_f16(af, b1, acc1, 0, 0, 0);
    }
    if (kg < 2) {   // C rows 0..7 valid (batch); cols = g*8+ju within wave
#pragma unroll
      for (int r = 0; r < 4; ++r) {
        gat[wave][kg * 4 + r][rowa] = acc0[r];
        gat[wave][kg * 4 + r][16 + rowa] = acc1[r];
      }
    }
    // wave-local read (lgkmcnt wait auto-inserted; no barrier)
    float gi = gat[wave][b][ju] + xi;
    float gf = gat[wave][b][8 + ju] + xf;
    float gg = gat[wave][b][16 + ju] + xg;
    float go = gat[wave][b][24 + ju] + xo;
    c = sigm(gf) * c + sigm(gi) * ftanh(gg);
    float h = sigm(go) * ftanh(c);

    float hn = __shfl_down(h, 1);
    if ((ju & 1) == 0)
      STOREX(hseq + (size_t)(t + 1) * 2048 + ((b * 512 + uglob) >> 1), packf16(h, hn));
    if (hs) hs[((size_t)b * S + t) * HH + uglob] = h;
  }
}

// 16-unit WG (encoder L1). Wave w owns units [w*4, w*4+4), ALL 4 gates.
// K-concat [Whh1|Wih1]: LDS W[64][1032]; row r = w*16 + g*4 + ju.
static __device__ __forceinline__ void lstm_l1(
    int wg, const float* __restrict__ gb, const f16* __restrict__ Wih,
    const f16* __restrict__ Whh, const u32* __restrict__ hin,
    u32* __restrict__ hseq, float* __restrict__ hs, int S) {
  extern __shared__ char smem[];
  f16 (*W)[1032] = (f16(*)[1032])smem;                      // 132,096 B
  f16 (*H)[1032] = (f16(*)[1032])(smem + 132096);           //  16,512 B
  float (*gat)[8][20] = (float(*)[8][20])(smem + 132096 + 16512); // 2,560 B
  const int tid = threadIdx.x;
  const int u0 = wg * 16;
  const int wave = tid >> 6, lane = tid & 63;
  const int rowa = lane & 15, kg = lane >> 4;
  const int b = lane >> 2, ju = lane & 3;   // valid for lane < 32
  const int uglob = u0 + wave * 4 + ju;

  // stage weights: LDS row r = w*16 + g*4 + ju
  for (int idx = tid; idx < 64 * 64; idx += 256) {
    int r = idx >> 6, ck = idx & 63;
    int w = r >> 4, g = (r >> 2) & 3, u = r & 3;
    size_t grow = (size_t)(g * 512 + u0 + w * 4 + u) * 512;
    *(uint4*)&W[r][ck * 8]       = *(const uint4*)(Whh + grow + ck * 8);
    *(uint4*)&W[r][512 + ck * 8] = *(const uint4*)(Wih + grow + ck * 8);
  }
  // bias hoist (lanes < 32)
  float gbi = 0.f, gbf = 0.f, gbg = 0.f, gbo = 0.f;
  if (lane < 32) {
    gbi = gb[uglob]; gbf = gb[512 + uglob];
    gbg = gb[1024 + uglob]; gbo = gb[1536 + uglob];
  }
  __syncthreads();

  float c = 0.f;
  for (int t = 0; t < S; ++t) {
    const u32* hbS = hseq + (size_t)t * 2048;
    const u32* hbU = hin + (size_t)(t + 1) * 2048;
    // guard phase: 32 threads on self producers, 16 on upstream producers
    if (tid < 32)       guard_spin(hbS + tid * 8);
    else if (tid < 48)  guard_spin(hbU + (tid - 32) * 16);
    __syncthreads();   // also protects H from next-step overwrite
    // verify + stage (16 words in flight)
    const u32* ptr[16];
    u32 vv[16];
#pragma unroll
    for (int k = 0; k < 8; ++k) {
      int idx = tid + k * 256;
      int r = idx >> 8, cu = idx & 255;
      ptr[k] = hbS + r * 256 + cu;
      ptr[k + 8] = hbU + r * 256 + cu;
    }
    poll_batch<16>(ptr, vv);
#pragma unroll
    for (int k = 0; k < 8; ++k) {
      int idx = tid + k * 256;
      int r = idx >> 8, cu = idx & 255;
      ((u32*)H)[r * 516 + cu] = vv[k];
      ((u32*)H)[r * 516 + 256 + cu] = vv[k + 8];
    }
    __syncthreads();  // B2

    // split accumulators: two independent 16-long MFMA chains
    f32x4 accA = {0.f, 0.f, 0.f, 0.f}, accB = {0.f, 0.f, 0.f, 0.f};
#pragma unroll
    for (int kf = 0; kf < 16; ++kf) {
      f16x8 afA = {}, afB = {};
      if (rowa < 8) {
        afA = *(const f16x8*)&H[rowa][kf * 32 + kg * 8];
        afB = *(const f16x8*)&H[rowa][(kf + 16) * 32 + kg * 8];
      }
      f16x8 bfA = *(const f16x8*)&W[wave * 16 + rowa][kf * 32 + kg * 8];
      f16x8 bfB = *(const f16x8*)&W[wave * 16 + rowa][(kf + 16) * 32 + kg * 8];
      accA = __builtin_amdgcn_mfma_f32_16x16x32_f16(afA, bfA, accA, 0, 0, 0);
      accB = __builtin_amdgcn_mfma_f32_16x16x32_f16(afB, bfB, accB, 0, 0, 0);
    }
    if (kg < 2) {   // cols = g*4+ju within wave
#pragma unroll
      for (int r = 0; r < 4; ++r) gat[wave][kg * 4 + r][rowa] = accA[r] + accB[r];
    }
    // wave-local scalar phase (no barrier)
    if (lane < 32) {
      float gi = gat[wave][b][ju]      + gbi;
      float gf = gat[wave][b][4 + ju]  + gbf;
      float gg = gat[wave][b][8 + ju]  + gbg;
      float go = gat[wave][b][12 + ju] + gbo;
      c = sigm(gf) * c + sigm(gi) * ftanh(gg);
      float h = sigm(go) * ftanh(c);
      float hn = __shfl_down(h, 1);
      if ((ju & 1) == 0)
        STOREX(hseq + (size_t)(t + 1) * 2048 + (b * 256 + (uglob >> 1)), packf16(h, hn));
      hs[((size_t)b * S + t) * HH + uglob] = h;
    }
  }
}

// all three LSTMs in one dispatch (64 WGs)
__global__ __launch_bounds__(256, 1) void k_lstm3(
    const float* xp0, const f16* Whh0, u32* hseq0,
    const float* b1, const f16* Wih1, const f16* Whh1, u32* hseq1, float* h1s,
    const float* xpd, const f16* Whhd, u32* hseqD, float* hds) {
  int g = blockIdx.x;
  if (g < 16)      lstm_16(g, xp0, Whh0, hseq0, nullptr, TT);
  else if (g < 48) lstm_l1(g - 16, b1, Wih1, Whh1, hseq0, hseq1, h1s, TT);
  else             lstm_16(g - 48, xpd, Whhd, hseqD, hds, UU1);
}

// ------------------------------ fused joint --------------------------------
// 64-row M-tile, swapped operands: A = jW2 (v rows), B = Z (m rows)
// -> C row = v, col = m -> per-lane f32x4 nontemporal stores.
__global__ __launch_bounds__(512) void k_joint(
    const float* __restrict__ pre_enc,   // [B*T][512]   (no bias)
    const float* __restrict__ pre_dec,   // [B*65][512]  (jb1 folded in)
    const f16* __restrict__ jW2,         // [1024][512] f16
    const float* __restrict__ jb2,
    float* __restrict__ out) {
  extern __shared__ char smem[];
  f16 (*Z)[520] = (f16(*)[520])smem;     // 66,560 B -> 2 blocks/CU
  int tid = threadIdx.x;
  int m0 = blockIdx.x * 64;
  {
    int r = tid >> 3, q = tid & 7;       // 8 threads per row, 64 cols each
    int m = m0 + r;
    int bb = m / (TT * UU1);
    int rem = m % (TT * UU1);
    int t = rem / UU1, u = rem % UU1;
    const float* pe = pre_enc + ((size_t)bb * TT + t) * JJ + q * 64;
    const float* pd = pre_dec + ((size_t)bb * UU1 + u) * JJ + q * 64;
    for (int i = 0; i < 64; i += 8) {
      float4 e0 = *(const float4*)(pe + i);
      float4 e1 = *(const float4*)(pe + i + 4);
      float4 d0 = *(const float4*)(pd + i);
      float4 d1 = *(const float4*)(pd + i + 4);
      float z0 = ftanh(e0.x + d0.x), z1 = ftanh(e0.y + d0.y);
      float z2 = ftanh(e0.z + d0.z), z3 = ftanh(e0.w + d0.w);
      float z4 = ftanh(e1.x + d1.x), z5 = ftanh(e1.y + d1.y);
      float z6 = ftanh(e1.z + d1.z), z7 = ftanh(e1.w + d1.w);
      uint4 p; p.x = packf16(z0, z1); p.y = packf16(z2, z3);
      p.z = packf16(z4, z5); p.w = packf16(z6, z7);
      *(uint4*)&Z[r][q * 64 + i] = p;
    }
  }
  __syncthreads();
  int wave = tid >> 6, lane = tid & 63;
  int wm = wave >> 2, wn = wave & 3;     // 2 x 4 waves over 64 m x 256 v
  int rowa = lane & 15, kg = lane >> 4;
  for (int ch = 0; ch < 4; ++ch) {       // 4 N-chunks of 256
    f32x4 acc[4][2] = {};
    int nb = ch * 256 + wn * 64;
    for (int kf = 0; kf < 16; ++kf) {
      f16x8 af[4], bf[2];
#pragma unroll
      for (int nt = 0; nt < 4; ++nt)
        af[nt] = *(const f16x8*)(jW2 + (size_t)(nb + nt * 16 + rowa) * JJ + kf * 32 + kg * 8);
#pragma unroll
      for (int mt = 0; mt < 2; ++mt)
        bf[mt] = *(const f16x8*)&Z[wm * 32 + mt * 16 + rowa][kf * 32 + kg * 8];
#pragma unroll
      for (int nt = 0; nt < 4; ++nt)
#pragma unroll
        for (int mt = 0; mt < 2; ++mt)
          acc[nt][mt] = __builtin_amdgcn_mfma_f32_16x16x32_f16(af[nt], bf[mt], acc[nt][mt], 0, 0, 0);
    }
#pragma unroll
    for (int nt = 0; nt < 4; ++nt) {
      int v = nb + nt * 16 + kg * 4;
      float4 bv = *(const float4*)(jb2 + v);
#pragma unroll
      for (int mt = 0; mt < 2; ++mt) {
        int m = m0 + wm * 32 + mt * 16 + rowa;
        f32x4 st;
        st[0] = acc[nt][mt][0] + bv.x;
        st[1] = acc[nt][mt][1] + bv.y;
        st[2] = acc[nt][mt][2] + bv.z;
        st[3] = acc[nt][mt][3] + bv.w;
        __builtin_nontemporal_store(st, (f32x4*)(out + (size_t)m * VV + v));
      }
    }
  }
}

// ------------------------------- host side ---------------------------------
extern "C" void kernel_launch(void* const* d_in, const int* in_sizes, int n_in,
                              void* d_out, int out_size, void* d_ws, size_t ws_size,
                              hipStream_t stream) {
  const float* xs    = (const float*)d_in[0];
  const int*   ys    = (const int*)d_in[1];
  const float* Wih0  = (const float*)d_in[2];
  const float* Whh0  = (const float*)d_in[3];
  const float* b0    = (const float*)d_in[4];
  const float* Wih1  = (const float*)d_in[5];
  const float* Whh1  = (const float*)d_in[6];
  const float* b1    = (const float*)d_in[7];
  const float* encPW = (const float*)d_in[8];
  const float* encPb = (const float*)d_in[9];
  const float* embed = (const float*)d_in[10];
  const float* dWih  = (const float*)d_in[11];
  const float* dWhh  = (const float*)d_in[12];
  const float* db    = (const float*)d_in[13];
  const float* dPW   = (const float*)d_in[14];
  const float* dPb   = (const float*)d_in[15];
  const float* jW1   = (const float*)d_in[16];
  const float* jb1   = (const float*)d_in[17];
  const float* jW2   = (const float*)d_in[18];
  const float* jb2   = (const float*)d_in[19];
  float* out = (float*)d_out;

  char* base = (char*)d_ws;
  size_t off = 0;
  auto alc = [&](size_t bytes) -> char* {
    char* p = base + off;
    off = (off + bytes + 255) & ~(size_t)255;
    return p;
  };
  f16* Wih0h = (f16*)alc((size_t)2048 * 80 * 2);
  f16* Whh0h = (f16*)alc((size_t)2048 * 512 * 2);
  f16* Wih1h = (f16*)alc((size_t)2048 * 512 * 2);
  f16* Whh1h = (f16*)alc((size_t)2048 * 512 * 2);
  f16* dWihh = (f16*)alc((size_t)2048 * 512 * 2);
  f16* dWhhh = (f16*)alc((size_t)2048 * 512 * 2);
  f16* ePWh  = (f16*)alc((size_t)512 * 512 * 2);
  f16* dPWh  = (f16*)alc((size_t)512 * 512 * 2);
  f16* jW1h  = (f16*)alc((size_t)512 * 1024 * 2);
  f16* jW2h  = (f16*)alc((size_t)1024 * 512 * 2);
  float* e    = (float*)alc((size_t)520 * 512 * 4);
  float* xp0  = (float*)alc((size_t)2048 * 2048 * 4);
  float* xpd  = (float*)alc((size_t)520 * 2048 * 4);
  float* h1s  = (float*)alc((size_t)2048 * 512 * 4);
  float* hds  = (float*)alc((size_t)520 * 512 * 4);
  float* henc = (float*)alc((size_t)2048 * 512 * 4);
  float* hdec = (float*)alc((size_t)520 * 512 * 4);
  float* penc = (float*)alc((size_t)2048 * 512 * 4);
  float* pdec = (float*)alc((size_t)520 * 512 * 4);
  // sentinel-synced h sequences (contiguous)
  u32* hseq0 = (u32*)alc((size_t)(TT + 1) * 2048 * 4);   // [257][2048]
  u32* hseq1 = (u32*)alc((size_t)(TT + 1) * 2048 * 4);   // [257][2048]
  u32* hseqD = (u32*)alc((size_t)(UU1 + 1) * 2048 * 4);  // [66][2048]
  if (off > ws_size) return;

  // 1) sentinel init (one launch): fill + zero slot 0 of each sequence
  {
    int n = (int)(((TT + 1) * 2 + (UU1 + 1)) * 2048);
    int z1 = (int)(hseq1 - hseq0), z2 = (int)(hseqD - hseq0);
    k_init<<<dim3((n + 255) / 256), dim3(256), 0, stream>>>(hseq0, n, z1, z2);
  }
  // 2) cast all weights to f16 in ONE launch
  {
    CastArgs ca;
    auto seg = [&](int i, const float* s, f16* d, size_t n) {
      ca.seg[i].s = s; ca.seg[i].d = d; ca.seg[i].n4 = (int)(n / 4);
    };
    seg(0, Wih0, Wih0h, (size_t)2048 * 80);
    seg(1, Whh0, Whh0h, (size_t)2048 * 512);
    seg(2, Wih1, Wih1h, (size_t)2048 * 512);
    seg(3, Whh1, Whh1h, (size_t)2048 * 512);
    seg(4, dWih, dWihh, (size_t)2048 * 512);
    seg(5, dWhh, dWhhh, (size_t)2048 * 512);
    seg(6, encPW, ePWh, (size_t)512 * 512);
    seg(7, dPW, dPWh, (size_t)512 * 512);
    seg(8, jW1, jW1h, (size_t)512 * 1024);
    seg(9, jW2, jW2h, (size_t)1024 * 512);
    int total4 = 0;
    for (int i = 0; i < 10; ++i) total4 += ca.seg[i].n4;
    k_cast_all<<<dim3((total4 + 255) / 256), dim3(256), 0, stream>>>(ca, total4);
  }

  // 3) embedding (decoder input)
  k_embed<<<dim3(520), dim3(128), 0, stream>>>(ys, embed, e);

  auto gemm = [&](const float* A, const f16* B, const float* bias, float* C,
                  int M, int N, int K, int lda, int ldb) {
    k_gemm<<<dim3(N / 128, (M + 127) / 128), dim3(256), 0, stream>>>(
        A, B, bias, C, M, N, K, lda, ldb);
  };

  // 4) input projections for enc L0 and decoder
  gemm(xs, Wih0h, b0, xp0, 2048, 2048, 80, 80, 80);
  gemm(e, dWihh, db, xpd, 520, 2048, 512, 512, 512);

  // 5) all three LSTMs, sentinel-pipelined, one dispatch (64 WGs)
  k_lstm3<<<dim3(64), dim3(256), 151168, stream>>>(
      xp0, Whh0h, hseq0,
      b1, Wih1h, Whh1h, hseq1, h1s,
      xpd, dWhhh, hseqD, hds);

  // 6) projections / joint pre-activations
  gemm(h1s, ePWh, encPb, henc, 2048, 512, 512, 512, 512);
  gemm(henc, jW1h, nullptr, penc, 2048, 512, 512, 512, 1024);
  gemm(hds, dPWh, dPb, hdec, 520, 512, 512, 512, 512);
  gemm(hdec, jW1h + 512, jb1, pdec, 520, 512, 512, 512, 1024);  // jb1 folded

  // 7) fused joint: z = tanh(penc+pdec) ; out = z @ jW2^T + jb2
  k_joint<<<dim3(2080), dim3(512), 66560, stream>>>(penc, pdec, jW2h, jb2, out);
}